// Round 13
// baseline (2500.246 us; speedup 1.0000x reference)
//
#include <hip/hip_runtime.h>

// Problem dims
#define V_ 50257
#define E_ 512
#define H_ 1024
#define LM_ 128
#define LC_ 256
#define NBLK 256   // recurrence blocks: 1 per CU, 4 h-outputs each
#define ROWS 12    // 3 gates x 4 outputs
#define AREP 16    // a-accumulator replicas (contention divisor)
#define NT_OUT 786 // out_gemm col-tiles

typedef __attribute__((ext_vector_type(8))) short short8;
typedef __attribute__((ext_vector_type(4))) float f32x4;
typedef unsigned long long u64;

__device__ __forceinline__ unsigned short f2bf(float x) {
  union { float f; unsigned u; } v; v.f = x;
  unsigned r = v.u + 0x7fffu + ((v.u >> 16) & 1u);   // round-to-nearest-even
  return (unsigned short)(r >> 16);
}
__device__ __forceinline__ float bflo(unsigned u) { union { unsigned u; float f; } v; v.u = u << 16; return v.f; }
__device__ __forceinline__ float bfhi(unsigned u) { union { unsigned u; float f; } v; v.u = u & 0xffff0000u; return v.f; }

__device__ __forceinline__ int grow4(int s, int i0) {
  return (s < 4) ? (i0 + s) : (s < 8) ? (1024 + i0 + (s - 4)) : (2048 + i0 + (s - 8));
}

// relaxed agent-scope ops (served at coherence point; no fences -> no L2 flush/inv)
__device__ __forceinline__ void st_u32(unsigned* p, unsigned v) {
  __hip_atomic_store(p, v, __ATOMIC_RELAXED, __HIP_MEMORY_SCOPE_AGENT);
}
__device__ __forceinline__ void st_u64(u64* p, u64 v) {
  __hip_atomic_store(p, v, __ATOMIC_RELAXED, __HIP_MEMORY_SCOPE_AGENT);
}
__device__ __forceinline__ u64 ld_u64(const u64* p) {
  return __hip_atomic_load(p, __ATOMIC_RELAXED, __HIP_MEMORY_SCOPE_AGENT);
}
__device__ __forceinline__ unsigned ld_u32(const unsigned* p) {
  return __hip_atomic_load(p, __ATOMIC_RELAXED, __HIP_MEMORY_SCOPE_AGENT);
}
__device__ __forceinline__ void atom_add_f32(float* p, float v) {
  (void)__hip_atomic_fetch_add(p, v, __ATOMIC_RELAXED, __HIP_MEMORY_SCOPE_AGENT);
}

// ---------------- decoder token table ----------------
__global__ void build_dec_tok(const int* __restrict__ tgt, int* __restrict__ dtok) {
  int t = threadIdx.x;
  dtok[t] = (t == 0) ? 0 : (t == 1 ? tgt[LC_ - 1] : tgt[t - 2]);
}

// ---------------- gathered f32 GEMM: C[M,N] = A[rows][K] @ B[N,K]^T + bias ----------------
__global__ __launch_bounds__(256) void gemm_g(const float* __restrict__ A, int lda,
                                              const int* __restrict__ ridx,
                                              const float* __restrict__ B, int ldb,
                                              const float* __restrict__ bias,
                                              float* __restrict__ C, int ldc, int K) {
  __shared__ float As[16][68];
  __shared__ float Bs[16][68];
  const int bm = blockIdx.y * 64, bn = blockIdx.x * 64;
  const int tid = threadIdx.x;
  const int tx = tid & 15, ty = tid >> 4;
  const int lm = tid & 63, lk = (tid >> 6) * 4;
  const int arow = ridx ? ridx[bm + lm] : (bm + lm);
  const float* Arow = A + (size_t)arow * lda;
  float acc[4][4] = {};
  for (int k0 = 0; k0 < K; k0 += 16) {
    float4 av = *(const float4*)&Arow[k0 + lk];
    float4 bv = *(const float4*)&B[(size_t)(bn + lm) * ldb + k0 + lk];
    As[lk + 0][lm] = av.x; As[lk + 1][lm] = av.y; As[lk + 2][lm] = av.z; As[lk + 3][lm] = av.w;
    Bs[lk + 0][lm] = bv.x; Bs[lk + 1][lm] = bv.y; Bs[lk + 2][lm] = bv.z; Bs[lk + 3][lm] = bv.w;
    __syncthreads();
#pragma unroll
    for (int kk = 0; kk < 16; ++kk) {
      float4 a4 = *(const float4*)&As[kk][ty * 4];
      float4 b4 = *(const float4*)&Bs[kk][tx * 4];
      acc[0][0] += a4.x * b4.x; acc[0][1] += a4.x * b4.y; acc[0][2] += a4.x * b4.z; acc[0][3] += a4.x * b4.w;
      acc[1][0] += a4.y * b4.x; acc[1][1] += a4.y * b4.y; acc[1][2] += a4.y * b4.z; acc[1][3] += a4.y * b4.w;
      acc[2][0] += a4.z * b4.x; acc[2][1] += a4.z * b4.y; acc[2][2] += a4.z * b4.z; acc[2][3] += a4.z * b4.w;
      acc[3][0] += a4.w * b4.x; acc[3][1] += a4.w * b4.y; acc[3][2] += a4.w * b4.z; acc[3][3] += a4.w * b4.w;
    }
    __syncthreads();
  }
#pragma unroll
  for (int i = 0; i < 4; ++i) {
#pragma unroll
    for (int j = 0; j < 4; ++j) {
      int gm = bm + ty * 4 + i, gn = bn + tx * 4 + j;
      float bv = bias ? bias[gn] : 0.f;
      C[(size_t)gm * ldc + gn] = acc[i][j] + bv;
    }
  }
}

// ---------------- dual-output gathered GEMM: xE (bx<16) and aE (bx>=16) from dec_emb ----
__global__ __launch_bounds__(256) void gemm_dual(const float* __restrict__ A, int lda,
                                                 const int* __restrict__ ridx,
                                                 const float* __restrict__ combW,
                                                 const float* __restrict__ comb_b,
                                                 const float* __restrict__ attnW,
                                                 const float* __restrict__ attn_b,
                                                 float* __restrict__ xE,
                                                 float* __restrict__ aE, int K) {
  __shared__ float As[16][68];
  __shared__ float Bs[16][68];
  const int bm = blockIdx.y * 64;
  const bool is_x = blockIdx.x < 16;
  const int bn = (is_x ? blockIdx.x : (blockIdx.x - 16)) * 64;
  const float* B = is_x ? combW : attnW;
  const int ldb = 2048;
  const float* bias = is_x ? comb_b : attn_b;
  float* C = is_x ? xE : aE;
  const int ldc = is_x ? 1024 : 128;
  const int tid = threadIdx.x;
  const int tx = tid & 15, ty = tid >> 4;
  const int lm = tid & 63, lk = (tid >> 6) * 4;
  const int arow = ridx[bm + lm];
  const float* Arow = A + (size_t)arow * lda;
  float acc[4][4] = {};
  for (int k0 = 0; k0 < K; k0 += 16) {
    float4 av = *(const float4*)&Arow[k0 + lk];
    float4 bv = *(const float4*)&B[(size_t)(bn + lm) * ldb + k0 + lk];
    As[lk + 0][lm] = av.x; As[lk + 1][lm] = av.y; As[lk + 2][lm] = av.z; As[lk + 3][lm] = av.w;
    Bs[lk + 0][lm] = bv.x; Bs[lk + 1][lm] = bv.y; Bs[lk + 2][lm] = bv.z; Bs[lk + 3][lm] = bv.w;
    __syncthreads();
#pragma unroll
    for (int kk = 0; kk < 16; ++kk) {
      float4 a4 = *(const float4*)&As[kk][ty * 4];
      float4 b4 = *(const float4*)&Bs[kk][tx * 4];
      acc[0][0] += a4.x * b4.x; acc[0][1] += a4.x * b4.y; acc[0][2] += a4.x * b4.z; acc[0][3] += a4.x * b4.w;
      acc[1][0] += a4.y * b4.x; acc[1][1] += a4.y * b4.y; acc[1][2] += a4.y * b4.z; acc[1][3] += a4.y * b4.w;
      acc[2][0] += a4.z * b4.x; acc[2][1] += a4.z * b4.y; acc[2][2] += a4.z * b4.z; acc[2][3] += a4.z * b4.w;
      acc[3][0] += a4.w * b4.x; acc[3][1] += a4.w * b4.y; acc[3][2] += a4.w * b4.z; acc[3][3] += a4.w * b4.w;
    }
    __syncthreads();
  }
#pragma unroll
  for (int i = 0; i < 4; ++i) {
#pragma unroll
    for (int j = 0; j < 4; ++j) {
      int gm = bm + ty * 4 + i, gn = bn + tx * 4 + j;
      C[(size_t)gm * ldc + gn] = acc[i][j] + bias[gn];
    }
  }
}

// ---------------- encoder recurrence: self-validating packets + gi prefetch ----------------
__global__ __launch_bounds__(256) void enc_rnn(const float* __restrict__ Whh,
                                               const float* __restrict__ bhh,
                                               const float* __restrict__ gi,
                                               u64* __restrict__ epk,
                                               float* __restrict__ outs) {
  __shared__ unsigned short Whl[ROWS][1024];  // 24 KB
  __shared__ unsigned h_sh[512];
  __shared__ float h_own[4];
  __shared__ float bh[ROWS];
  __shared__ float ghl[ROWS];
  const int b = blockIdx.x, tid = threadIdx.x;
  const int w = tid >> 6, l = tid & 63;
  const int i0 = b * 4;
  for (int idx = tid; idx < ROWS * 1024; idx += 256) {
    int s = idx >> 10, c = idx & 1023;
    Whl[s][c] = f2bf(Whh[(size_t)grow4(s, i0) * H_ + c]);
  }
  if (tid < ROWS) bh[tid] = bhh[grow4(tid, i0)];
  if (tid < 4) h_own[tid] = 0.f;
  __syncthreads();

  for (int t = 0; t < LM_; ++t) {
    float gr = 0.f, gz = 0.f, gn_ = 0.f;
    if (tid < 4) {
      const float* git = gi + (size_t)t * 3072;
      gr = git[i0 + tid]; gz = git[1024 + i0 + tid]; gn_ = git[2048 + i0 + tid];
    }
    if (t == 0) {
      h_sh[2 * tid] = 0u; h_sh[2 * tid + 1] = 0u;
    } else {
      const u64* pb = epk + (size_t)(t & 1) * 512 + 2 * tid;
      const unsigned g = (unsigned)t;
      u64 q0, q1;
      for (;;) {
        q0 = ld_u64(pb); q1 = ld_u64(pb + 1);
        if ((unsigned)(q0 >> 32) == g && (unsigned)(q1 >> 32) == g) break;
        __builtin_amdgcn_s_sleep(1);
      }
      h_sh[2 * tid] = (unsigned)q0;
      h_sh[2 * tid + 1] = (unsigned)q1;
    }
    __syncthreads();

    for (int s = w; s < ROWS; s += 4) {
      float acc = 0.f;
#pragma unroll
      for (int e = 0; e < 8; ++e) {
        unsigned u = *(const unsigned*)&Whl[s][2 * (e * 64 + l)];
        unsigned hv = h_sh[e * 64 + l];
        acc += bflo(u) * bflo(hv) + bfhi(u) * bfhi(hv);
      }
#pragma unroll
      for (int off = 32; off; off >>= 1) acc += __shfl_xor(acc, off);
      if (l == 0) ghl[s] = acc;
    }
    __syncthreads();
    if (tid < 4) {
      int i = tid, ig = i0 + i;
      float hr = ghl[i] + bh[i], hz = ghl[4 + i] + bh[4 + i], hn = ghl[8 + i] + bh[8 + i];
      float r = 1.f / (1.f + expf(-(gr + hr)));
      float z = 1.f / (1.f + expf(-(gz + hz)));
      float n = tanhf(gn_ + r * hn);
      float hpv = (1.f - z) * n + z * h_own[i];
      h_own[i] = hpv;
      float v0 = __shfl(hpv, 0), v1 = __shfl(hpv, 1);
      float v2 = __shfl(hpv, 2), v3 = __shfl(hpv, 3);
      if (tid == 0) {
        u64 gg = (u64)(unsigned)(t + 1) << 32;
        u64* pb = epk + (size_t)((t + 1) & 1) * 512 + 2 * b;
        st_u64(pb,     gg | (u64)((unsigned)f2bf(v0) | ((unsigned)f2bf(v1) << 16)));
        st_u64(pb + 1, gg | (u64)((unsigned)f2bf(v2) | ((unsigned)f2bf(v3) << 16)));
      }
      outs[(size_t)t * H_ + ig] = hpv;
    }
  }
}

// ---------------- decoder recurrence: 4 barriers/step, redundant gates, early atomics ----
__global__ __launch_bounds__(256) void dec_rnn(const float* __restrict__ Whh,
                                               const float* __restrict__ bhh,
                                               const float* __restrict__ attn_W,
                                               const float* __restrict__ G,
                                               const float* __restrict__ P1,
                                               const float* __restrict__ aE,
                                               const float* __restrict__ hfin,
                                               float* __restrict__ a_acc,
                                               u64* __restrict__ dpk,
                                               unsigned* __restrict__ dflags,
                                               unsigned short* __restrict__ Hs) {
  __shared__ unsigned short Whl[ROWS][1024];  // 24 KB
  __shared__ unsigned Ac[2 * 128];            // 1 KB
  __shared__ float Gl[ROWS][128];             // 6 KB
  __shared__ unsigned h_sh[512];              // 2 KB
  __shared__ float a_f[128];
  __shared__ float h_own[4];
  __shared__ float bh[ROWS];
  __shared__ float ghl[ROWS];
  __shared__ float giS[ROWS];
  const int b = blockIdx.x, tid = threadIdx.x;
  const int w = tid >> 6, l = tid & 63;
  const int i0 = b * 4;
  for (int idx = tid; idx < ROWS * 1024; idx += 256) {
    int s = idx >> 10, c = idx & 1023;
    Whl[s][c] = f2bf(Whh[(size_t)grow4(s, i0) * H_ + c]);
  }
  if (tid < 256) {
    int u = tid >> 7, j = tid & 127;
    float2 wv = *(const float2*)&attn_W[(size_t)j * 2048 + 1024 + i0 + 2 * u];
    Ac[tid] = (unsigned)f2bf(wv.x) | ((unsigned)f2bf(wv.y) << 16);
  }
  for (int idx = tid; idx < ROWS * 128; idx += 256) {
    int s = idx >> 7, c = idx & 127;
    Gl[s][c] = G[(size_t)grow4(s, i0) * 128 + c];
  }
  if (tid < ROWS) bh[tid] = bhh[grow4(tid, i0)];
  if (tid < 4) h_own[tid] = hfin[i0 + tid];   // exact f32 encoder-final h
  __syncthreads();

  // prologue: a-partial adds for t=0 from own h0 chunk, then a-flag = 1
  {
    float h0 = h_own[0], h1 = h_own[1], h2 = h_own[2], h3 = h_own[3];
    if (tid < 128) {
      unsigned w0 = Ac[tid], w1 = Ac[128 + tid];
      float a0 = bflo(w0) * h0 + bfhi(w0) * h1 + bflo(w1) * h2 + bfhi(w1) * h3;
      atom_add_f32(&a_acc[(b & (AREP - 1)) * 128 + tid], a0);
    }
    __syncthreads();  // drain atomics
    if (tid == 0) st_u32(&dflags[b * 16], 1u);
  }

  for (int t = 0; t < LC_; ++t) {
    // ---- snapshot own h_t; wave0 flag check + a_acc/aE loads; P1 prefetch ----
    float hown0 = h_own[0], hown1 = h_own[1], hown2 = h_own[2], hown3 = h_own[3];
    u64 aacc[16]; u64 aEv = 0;
    if (tid < 64) {
      const unsigned need = (unsigned)(t + 1);
      for (;;) {
        unsigned f0 = ld_u32(&dflags[tid * 16]);
        unsigned f1 = ld_u32(&dflags[(tid + 64) * 16]);
        unsigned f2 = ld_u32(&dflags[(tid + 128) * 16]);
        unsigned f3 = ld_u32(&dflags[(tid + 192) * 16]);
        unsigned mn = min(min(f0, f1), min(f2, f3));
        if (__all((int)(mn >= need))) break;
        __builtin_amdgcn_s_sleep(1);
      }
      const u64* ab = (const u64*)(a_acc + (size_t)t * (AREP * 128)) + l;
#pragma unroll
      for (int r = 0; r < AREP; ++r) aacc[r] = ld_u64(ab + r * 64);
      float2 ae2 = *(const float2*)&aE[(size_t)t * LM_ + 2 * l];
      aEv = ((u64)__float_as_uint(ae2.y) << 32) | (u64)__float_as_uint(ae2.x);
    }
    float p1p[3];
    if (l == 0) {
#pragma unroll
      for (int k = 0; k < 3; ++k) p1p[k] = P1[(size_t)t * 3072 + grow4(w + 4 * k, i0)];
    } else {
      p1p[0] = p1p[1] = p1p[2] = 0.f;
    }
    // ---- h arrival: self-validating packet poll (t=0: hfin) ----
    if (t == 0) {
      float4 hv = ((const float4*)hfin)[tid];
      h_sh[2 * tid] = (unsigned)f2bf(hv.x) | ((unsigned)f2bf(hv.y) << 16);
      h_sh[2 * tid + 1] = (unsigned)f2bf(hv.z) | ((unsigned)f2bf(hv.w) << 16);
    } else {
      const u64* pb = dpk + (size_t)(t & 1) * 512 + 2 * tid;
      const unsigned g = (unsigned)t;
      u64 q0, q1;
      for (;;) {
        q0 = ld_u64(pb); q1 = ld_u64(pb + 1);
        if ((unsigned)(q0 >> 32) == g && (unsigned)(q1 >> 32) == g) break;
        __builtin_amdgcn_s_sleep(1);
      }
      h_sh[2 * tid] = (unsigned)q0;
      h_sh[2 * tid + 1] = (unsigned)q1;
    }
    __syncthreads();  // B1

    // ---- wave0: finish a_f; all: gh rows ----
    if (tid < 64) {
      float s0 = 0.f, s1 = 0.f;
#pragma unroll
      for (int r = 0; r < AREP; ++r) {
        s0 += __uint_as_float((unsigned)aacc[r]);
        s1 += __uint_as_float((unsigned)(aacc[r] >> 32));
      }
      a_f[2 * l] = s0 + __uint_as_float((unsigned)aEv);
      a_f[2 * l + 1] = s1 + __uint_as_float((unsigned)(aEv >> 32));
    }
    for (int s = w; s < ROWS; s += 4) {
      float acc = 0.f;
#pragma unroll
      for (int e = 0; e < 8; ++e) {
        unsigned u = *(const unsigned*)&Whl[s][2 * (e * 64 + l)];
        unsigned hv = h_sh[e * 64 + l];
        acc += bflo(u) * bflo(hv) + bfhi(u) * bfhi(hv);
      }
#pragma unroll
      for (int off = 32; off; off >>= 1) acc += __shfl_xor(acc, off);
      if (l == 0) ghl[s] = acc;
    }
    __syncthreads();  // B2

    // ---- softmax over a[128] (per-wave redundant) + gi = P1 + G.w ----
    float ax = a_f[2 * l], ay = a_f[2 * l + 1];
    float mx = fmaxf(ax, ay);
#pragma unroll
    for (int off = 32; off; off >>= 1) mx = fmaxf(mx, __shfl_xor(mx, off));
    float pe0 = expf(ax - mx), pe1 = expf(ay - mx);
    float zs = pe0 + pe1;
#pragma unroll
    for (int off = 32; off; off >>= 1) zs += __shfl_xor(zs, off);
    float w0 = pe0 / zs, w1 = pe1 / zs;
#pragma unroll
    for (int k = 0; k < 3; ++k) {
      int s = w + 4 * k;
      float2 g2 = *(const float2*)&Gl[s][2 * l];
      float acc = g2.x * w0 + g2.y * w1;
#pragma unroll
      for (int off = 32; off; off >>= 1) acc += __shfl_xor(acc, off);
      if (l == 0) giS[s] = acc + p1p[k];
    }
    __syncthreads();  // B3

    // ---- ALL threads redundantly compute the 4 gates; atomics + publish immediately ----
    float hp[4];
#pragma unroll
    for (int i = 0; i < 4; ++i) {
      float hold = (i == 0) ? hown0 : (i == 1) ? hown1 : (i == 2) ? hown2 : hown3;
      float hr = ghl[i] + bh[i], hz = ghl[4 + i] + bh[4 + i], hn = ghl[8 + i] + bh[8 + i];
      float r = 1.f / (1.f + expf(-(giS[i] + hr)));
      float z = 1.f / (1.f + expf(-(giS[4 + i] + hz)));
      float n = tanhf(giS[8 + i] + r * hn);
      hp[i] = (1.f - z) * n + z * hold;
    }
    if (t < LC_ - 1) {
      if (tid < 128) {   // a-partial atomics for t+1, issued without broadcast wait
        unsigned w0p = Ac[tid], w1p = Ac[128 + tid];
        float a0 = bflo(w0p) * hp[0] + bfhi(w0p) * hp[1] + bflo(w1p) * hp[2] + bfhi(w1p) * hp[3];
        atom_add_f32(&a_acc[(size_t)(t + 1) * (AREP * 128) + (b & (AREP - 1)) * 128 + tid], a0);
      }
      if (tid == 0) {
        u64 gg = (u64)(unsigned)(t + 1) << 32;
        u64* pb = dpk + (size_t)((t + 1) & 1) * 512 + 2 * b;
        st_u64(pb,     gg | (u64)((unsigned)f2bf(hp[0]) | ((unsigned)f2bf(hp[1]) << 16)));
        st_u64(pb + 1, gg | (u64)((unsigned)f2bf(hp[2]) | ((unsigned)f2bf(hp[3]) << 16)));
      }
    }
    if (tid < 4) {
      h_own[tid] = hp[tid];
      Hs[(size_t)t * H_ + i0 + tid] = f2bf(hp[tid]);
    }
    __syncthreads();  // B4: drains atomics + packet stores; h_own stable for next snapshot
    if (tid == 0) st_u32(&dflags[b * 16], (unsigned)(t + 2));
  }
}

// ---------------- MFMA GEMM (double-buffered) + fused softmax partials ----------------
__global__ __launch_bounds__(256) void out_gemm(const unsigned short* __restrict__ A,
                                                const float* __restrict__ Wf, int ldw,
                                                const float* __restrict__ bias,
                                                float* __restrict__ C,
                                                float* __restrict__ pmax,
                                                float* __restrict__ psum,
                                                int N, int K) {
  __shared__ unsigned short As[2][256][40];
  __shared__ unsigned short Bs[2][64][40];
  const int bn = blockIdx.x * 64, bx = blockIdx.x;
  const int tid = threadIdx.x, w = tid >> 6, l = tid & 63;
  const int NIT = K / 32;
  f32x4 acc[4][4];
#pragma unroll
  for (int mf = 0; mf < 4; ++mf)
#pragma unroll
    for (int nf = 0; nf < 4; ++nf) acc[mf][nf] = (f32x4){0.f, 0.f, 0.f, 0.f};

  const int bidx = tid + 0, bn_r0 = (tid) >> 3, bkc0 = tid & 7;
  const int bn_r1 = (tid + 256) >> 3, bkc1 = (tid + 256) & 7;
  (void)bidx;

  short8 ar[4];
  float4 fv[2];
  // prologue: load iter 0
  {
    const unsigned short* src = A + (size_t)tid * K;
#pragma unroll
    for (int kc = 0; kc < 4; ++kc) ar[kc] = *(const short8*)(src + kc * 8);
    int gn0 = bn + bn_r0, gn1 = bn + bn_r1;
    fv[0] = (gn0 < N) ? *(const float4*)&Wf[(size_t)gn0 * ldw + bkc0 * 4] : (float4){0, 0, 0, 0};
    fv[1] = (gn1 < N) ? *(const float4*)&Wf[(size_t)gn1 * ldw + bkc1 * 4] : (float4){0, 0, 0, 0};
#pragma unroll
    for (int kc = 0; kc < 4; ++kc) *(short8*)&As[0][tid][kc * 8] = ar[kc];
    uint2 p0, p1;
    p0.x = (unsigned)f2bf(fv[0].x) | ((unsigned)f2bf(fv[0].y) << 16);
    p0.y = (unsigned)f2bf(fv[0].z) | ((unsigned)f2bf(fv[0].w) << 16);
    p1.x = (unsigned)f2bf(fv[1].x) | ((unsigned)f2bf(fv[1].y) << 16);
    p1.y = (unsigned)f2bf(fv[1].z) | ((unsigned)f2bf(fv[1].w) << 16);
    *(uint2*)&Bs[0][bn_r0][bkc0 * 4] = p0;
    *(uint2*)&Bs[0][bn_r1][bkc1 * 4] = p1;
  }

  for (int it = 0; it < NIT; ++it) {
    const int cur = it & 1, nxt = cur ^ 1;
    __syncthreads();
    if (it + 1 < NIT) {
      int k0n = (it + 1) * 32;
      const unsigned short* src = A + (size_t)tid * K + k0n;
#pragma unroll
      for (int kc = 0; kc < 4; ++kc) ar[kc] = *(const short8*)(src + kc * 8);
      int gn0 = bn + bn_r0, gn1 = bn + bn_r1;
      fv[0] = (gn0 < N) ? *(const float4*)&Wf[(size_t)gn0 * ldw + k0n + bkc0 * 4] : (float4){0, 0, 0, 0};
      fv[1] = (gn1 < N) ? *(const float4*)&Wf[(size_t)gn1 * ldw + k0n + bkc1 * 4] : (float4){0, 0, 0, 0};
    }
    const int k8 = (l >> 4) * 8;
    short8 af4[4], bf4[4];
#pragma unroll
    for (int mf = 0; mf < 4; ++mf) af4[mf] = *(const short8*)&As[cur][w * 64 + mf * 16 + (l & 15)][k8];
#pragma unroll
    for (int nf = 0; nf < 4; ++nf) bf4[nf] = *(const short8*)&Bs[cur][nf * 16 + (l & 15)][k8];
#pragma unroll
    for (int mf = 0; mf < 4; ++mf)
#pragma unroll
      for (int nf = 0; nf < 4; ++nf)
        acc[mf][nf] = __builtin_amdgcn_mfma_f32_16x16x32_bf16(af4[mf], bf4[nf], acc[mf][nf], 0, 0, 0);
    if (it + 1 < NIT) {
#pragma unroll
      for (int kc = 0; kc < 4; ++kc) *(short8*)&As[nxt][tid][kc * 8] = ar[kc];
      uint2 p0, p1;
      p0.x = (unsigned)f2bf(fv[0].x) | ((unsigned)f2bf(fv[0].y) << 16);
      p0.y = (unsigned)f2bf(fv[0].z) | ((unsigned)f2bf(fv[0].w) << 16);
      p1.x = (unsigned)f2bf(fv[1].x) | ((unsigned)f2bf(fv[1].y) << 16);
      p1.y = (unsigned)f2bf(fv[1].z) | ((unsigned)f2bf(fv[1].w) << 16);
      *(uint2*)&Bs[nxt][bn_r0][bkc0 * 4] = p0;
      *(uint2*)&Bs[nxt][bn_r1][bkc1 * 4] = p1;
    }
  }
#pragma unroll
  for (int mf = 0; mf < 4; ++mf) {
#pragma unroll
    for (int i = 0; i < 4; ++i) {
      int m = w * 64 + mf * 16 + (l >> 4) * 4 + i;
      float v[4];
#pragma unroll
      for (int nf = 0; nf < 4; ++nf) {
        int n = bn + nf * 16 + (l & 15);
        float val = -3.4e38f;
        if (n < N) {
          val = acc[mf][nf][i] + bias[n];
          C[(size_t)m * N + n] = val;
        }
        v[nf] = val;
      }
      float mv = fmaxf(fmaxf(v[0], v[1]), fmaxf(v[2], v[3]));
#pragma unroll
      for (int off = 1; off < 16; off <<= 1) mv = fmaxf(mv, __shfl_xor(mv, off));
      float se = 0.f;
#pragma unroll
      for (int nf = 0; nf < 4; ++nf) se += (v[nf] > -1e38f) ? expf(v[nf] - mv) : 0.f;
#pragma unroll
      for (int off = 1; off < 16; off <<= 1) se += __shfl_xor(se, off);
      if ((l & 15) == 0) {
        pmax[(size_t)m * NT_OUT + bx] = mv;
        psum[(size_t)m * NT_OUT + bx] = se;
      }
    }
  }
}

// ---------------- combine partials -> stats ----------------
__global__ __launch_bounds__(256) void lsm_combine(const float* __restrict__ pmax,
                                                   const float* __restrict__ psum,
                                                   float* __restrict__ stats) {
  const int r = blockIdx.x, tid = threadIdx.x, w = tid >> 6, l = tid & 63;
  __shared__ float red[4];
  __shared__ float Msh;
  const float* pm = pmax + (size_t)r * NT_OUT;
  const float* ps = psum + (size_t)r * NT_OUT;
  float m = -3.4e38f;
  for (int j = tid; j < NT_OUT; j += 256) m = fmaxf(m, pm[j]);
#pragma unroll
  for (int off = 32; off; off >>= 1) m = fmaxf(m, __shfl_xor(m, off));
  if (l == 0) red[w] = m;
  __syncthreads();
  if (tid == 0) Msh = fmaxf(fmaxf(red[0], red[1]), fmaxf(red[2], red[3]));
  __syncthreads();
  float M = Msh;
  float s = 0.f;
  for (int j = tid; j < NT_OUT; j += 256) s += ps[j] * expf(pm[j] - M);
#pragma unroll
  for (int off = 32; off; off >>= 1) s += __shfl_xor(s, off);
  if (l == 0) red[w] = s;
  __syncthreads();
  if (tid == 0) {
    stats[r] = M;
    stats[256 + r] = logf(red[0] + red[1] + red[2] + red[3]);
  }
}

__global__ __launch_bounds__(256) void lsm_apply(float* __restrict__ C, const float* __restrict__ stats, int N) {
  int r = blockIdx.y;
  int ci = blockIdx.x * 256 + threadIdx.x;
  if (ci < N) {
    size_t idx = (size_t)r * N + ci;
    C[idx] = C[idx] - stats[r] - stats[256 + r];
  }
}

extern "C" void kernel_launch(void* const* d_in, const int* in_sizes, int n_in,
                              void* d_out, int out_size, void* d_ws, size_t ws_size,
                              hipStream_t stream) {
  (void)in_sizes; (void)n_in; (void)out_size; (void)ws_size;
  const int* motion = (const int*)d_in[0];
  const int* tgt = (const int*)d_in[1];
  const float* enc_emb = (const float*)d_in[2];
  const float* enc_Wih = (const float*)d_in[3];
  const float* enc_Whh = (const float*)d_in[4];
  const float* enc_bih = (const float*)d_in[5];
  const float* enc_bhh = (const float*)d_in[6];
  const float* dec_emb = (const float*)d_in[7];
  const float* dec_Wih = (const float*)d_in[8];
  const float* dec_Whh = (const float*)d_in[9];
  const float* dec_bih = (const float*)d_in[10];
  const float* dec_bhh = (const float*)d_in[11];
  const float* attn_W = (const float*)d_in[12];
  const float* attn_b = (const float*)d_in[13];
  const float* comb_W = (const float*)d_in[14];
  const float* comb_b = (const float*)d_in[15];
  const float* out_W = (const float*)d_in[16];
  const float* out_b = (const float*)d_in[17];
  float* out = (float*)d_out;

  // workspace layout (floats, 16B-aligned chunks)
  float* wsf = (float*)d_ws;
  size_t o = 0;
  auto F = [&](size_t n) { float* p = wsf + o; o += (n + 3) & ~(size_t)3; return p; };
  float* enc_gi = F(128 * 3072);
  float* enc_outs = F(128 * 1024);
  float* aE = F(256 * 128);
  float* xE = F(256 * 1024);
  float* P1 = F(256 * 3072);
  float* M2T = F(128 * 1024);
  float* Gm = F(3072 * 128);
  int* dec_tok = (int*)F(256);
  u64* epk = (u64*)F(2048);                   // [2][256][2] u64 packets  } contiguous
  u64* dpk = (u64*)F(2048);                   //                          } for single
  unsigned* dflags = (unsigned*)F(4096);      // 256 flags, 64B apart     } memset
  float* a_acc = F(LC_ * AREP * 128);         // per-step 16-replica a accumulators
  float* stats = F(512);
  float* pmax = F(256 * NT_OUT);
  float* psum = F(256 * NT_OUT);
  unsigned short* Hs = (unsigned short*)F(256 * 1024 / 2);

  // fresh packets/flags/accumulators each launch (epk..a_acc contiguous)
  hipMemsetAsync(epk, 0, (2048 + 2048 + 4096 + LC_ * AREP * 128) * sizeof(float), stream);

  // precompute (gather-fused GEMMs)
  build_dec_tok<<<1, 256, 0, stream>>>(tgt, dec_tok);
  gemm_g<<<dim3(48, 2), 256, 0, stream>>>(enc_emb, 512, motion, enc_Wih, 512, enc_bih, enc_gi, 3072, 512);
  gemm_dual<<<dim3(18, 4), 256, 0, stream>>>(dec_emb, 1024, dec_tok, comb_W, comb_b, attn_W, attn_b, xE, aE, 1024);
  gemm_g<<<dim3(48, 4), 256, 0, stream>>>(xE, 1024, nullptr, dec_Wih, 1024, dec_bih, P1, 3072, 1024);

  // encoder recurrence
  enc_rnn<<<NBLK, 256, 0, stream>>>(enc_Whh, enc_bhh, enc_gi, epk, enc_outs);

  // G = dec_Wih @ (comb_W[:,H:] @ enc_outs^T)
  gemm_g<<<dim3(16, 2), 256, 0, stream>>>(enc_outs, 1024, nullptr, comb_W + 1024, 2048, nullptr, M2T, 1024, 1024);
  gemm_g<<<dim3(2, 48), 256, 0, stream>>>(dec_Wih, 1024, nullptr, M2T, 1024, nullptr, Gm, 128, 1024);

  // decoder recurrence
  dec_rnn<<<NBLK, 256, 0, stream>>>(dec_Whh, dec_bhh, attn_W, Gm, P1, aE,
                                    enc_outs + (size_t)(LM_ - 1) * H_, a_acc, dpk, dflags, Hs);

  // output projection (+ fused softmax partials) + combine + apply
  out_gemm<<<NT_OUT, 256, 0, stream>>>(Hs, out_W, 1024, out_b, out, pmax, psum, V_, 1024);
  lsm_combine<<<256, 256, 0, stream>>>(pmax, psum, stats);
  lsm_apply<<<dim3(197, 256), 256, 0, stream>>>(out, stats, V_);
}

// Round 14
// 2332.974 us; speedup vs baseline: 1.0717x; 1.0717x over previous
//
#include <hip/hip_runtime.h>

// Problem dims
#define V_ 50257
#define E_ 512
#define H_ 1024
#define LM_ 128
#define LC_ 256
#define NBLK 256   // recurrence blocks: 1 per CU, 4 h-outputs each
#define ROWS 12    // 3 gates x 4 outputs
#define AREP 16    // a-accumulator replicas (contention divisor)
#define NT_OUT 786 // out_gemm col-tiles

typedef __attribute__((ext_vector_type(8))) short short8;
typedef __attribute__((ext_vector_type(4))) float f32x4;
typedef unsigned long long u64;

__device__ __forceinline__ unsigned short f2bf(float x) {
  union { float f; unsigned u; } v; v.f = x;
  unsigned r = v.u + 0x7fffu + ((v.u >> 16) & 1u);   // round-to-nearest-even
  return (unsigned short)(r >> 16);
}
__device__ __forceinline__ float bflo(unsigned u) { union { unsigned u; float f; } v; v.u = u << 16; return v.f; }
__device__ __forceinline__ float bfhi(unsigned u) { union { unsigned u; float f; } v; v.u = u & 0xffff0000u; return v.f; }

__device__ __forceinline__ int grow4(int s, int i0) {
  return (s < 4) ? (i0 + s) : (s < 8) ? (1024 + i0 + (s - 4)) : (2048 + i0 + (s - 8));
}

// relaxed agent-scope ops (served at coherence point; no fences -> no L2 flush/inv)
__device__ __forceinline__ void st_u32(unsigned* p, unsigned v) {
  __hip_atomic_store(p, v, __ATOMIC_RELAXED, __HIP_MEMORY_SCOPE_AGENT);
}
__device__ __forceinline__ void st_u64(u64* p, u64 v) {
  __hip_atomic_store(p, v, __ATOMIC_RELAXED, __HIP_MEMORY_SCOPE_AGENT);
}
__device__ __forceinline__ u64 ld_u64(const u64* p) {
  return __hip_atomic_load(p, __ATOMIC_RELAXED, __HIP_MEMORY_SCOPE_AGENT);
}
__device__ __forceinline__ unsigned ld_u32(const unsigned* p) {
  return __hip_atomic_load(p, __ATOMIC_RELAXED, __HIP_MEMORY_SCOPE_AGENT);
}
__device__ __forceinline__ void atom_add_f32(float* p, float v) {
  (void)__hip_atomic_fetch_add(p, v, __ATOMIC_RELAXED, __HIP_MEMORY_SCOPE_AGENT);
}

// ---------------- decoder token table ----------------
__global__ void build_dec_tok(const int* __restrict__ tgt, int* __restrict__ dtok) {
  int t = threadIdx.x;
  dtok[t] = (t == 0) ? 0 : (t == 1 ? tgt[LC_ - 1] : tgt[t - 2]);
}

// ---------------- gathered f32 GEMM: C[M,N] = A[rows][K] @ B[N,K]^T + bias ----------------
__global__ __launch_bounds__(256) void gemm_g(const float* __restrict__ A, int lda,
                                              const int* __restrict__ ridx,
                                              const float* __restrict__ B, int ldb,
                                              const float* __restrict__ bias,
                                              float* __restrict__ C, int ldc, int K) {
  __shared__ float As[16][68];
  __shared__ float Bs[16][68];
  const int bm = blockIdx.y * 64, bn = blockIdx.x * 64;
  const int tid = threadIdx.x;
  const int tx = tid & 15, ty = tid >> 4;
  const int lm = tid & 63, lk = (tid >> 6) * 4;
  const int arow = ridx ? ridx[bm + lm] : (bm + lm);
  const float* Arow = A + (size_t)arow * lda;
  float acc[4][4] = {};
  for (int k0 = 0; k0 < K; k0 += 16) {
    float4 av = *(const float4*)&Arow[k0 + lk];
    float4 bv = *(const float4*)&B[(size_t)(bn + lm) * ldb + k0 + lk];
    As[lk + 0][lm] = av.x; As[lk + 1][lm] = av.y; As[lk + 2][lm] = av.z; As[lk + 3][lm] = av.w;
    Bs[lk + 0][lm] = bv.x; Bs[lk + 1][lm] = bv.y; Bs[lk + 2][lm] = bv.z; Bs[lk + 3][lm] = bv.w;
    __syncthreads();
#pragma unroll
    for (int kk = 0; kk < 16; ++kk) {
      float4 a4 = *(const float4*)&As[kk][ty * 4];
      float4 b4 = *(const float4*)&Bs[kk][tx * 4];
      acc[0][0] += a4.x * b4.x; acc[0][1] += a4.x * b4.y; acc[0][2] += a4.x * b4.z; acc[0][3] += a4.x * b4.w;
      acc[1][0] += a4.y * b4.x; acc[1][1] += a4.y * b4.y; acc[1][2] += a4.y * b4.z; acc[1][3] += a4.y * b4.w;
      acc[2][0] += a4.z * b4.x; acc[2][1] += a4.z * b4.y; acc[2][2] += a4.z * b4.z; acc[2][3] += a4.z * b4.w;
      acc[3][0] += a4.w * b4.x; acc[3][1] += a4.w * b4.y; acc[3][2] += a4.w * b4.z; acc[3][3] += a4.w * b4.w;
    }
    __syncthreads();
  }
#pragma unroll
  for (int i = 0; i < 4; ++i) {
#pragma unroll
    for (int j = 0; j < 4; ++j) {
      int gm = bm + ty * 4 + i, gn = bn + tx * 4 + j;
      float bv = bias ? bias[gn] : 0.f;
      C[(size_t)gm * ldc + gn] = acc[i][j] + bv;
    }
  }
}

// ---------------- dual-output gathered GEMM: xE (bx<16) and aE (bx>=16) from dec_emb ----
__global__ __launch_bounds__(256) void gemm_dual(const float* __restrict__ A, int lda,
                                                 const int* __restrict__ ridx,
                                                 const float* __restrict__ combW,
                                                 const float* __restrict__ comb_b,
                                                 const float* __restrict__ attnW,
                                                 const float* __restrict__ attn_b,
                                                 float* __restrict__ xE,
                                                 float* __restrict__ aE, int K) {
  __shared__ float As[16][68];
  __shared__ float Bs[16][68];
  const int bm = blockIdx.y * 64;
  const bool is_x = blockIdx.x < 16;
  const int bn = (is_x ? blockIdx.x : (blockIdx.x - 16)) * 64;
  const float* B = is_x ? combW : attnW;
  const int ldb = 2048;
  const float* bias = is_x ? comb_b : attn_b;
  float* C = is_x ? xE : aE;
  const int ldc = is_x ? 1024 : 128;
  const int tid = threadIdx.x;
  const int tx = tid & 15, ty = tid >> 4;
  const int lm = tid & 63, lk = (tid >> 6) * 4;
  const int arow = ridx[bm + lm];
  const float* Arow = A + (size_t)arow * lda;
  float acc[4][4] = {};
  for (int k0 = 0; k0 < K; k0 += 16) {
    float4 av = *(const float4*)&Arow[k0 + lk];
    float4 bv = *(const float4*)&B[(size_t)(bn + lm) * ldb + k0 + lk];
    As[lk + 0][lm] = av.x; As[lk + 1][lm] = av.y; As[lk + 2][lm] = av.z; As[lk + 3][lm] = av.w;
    Bs[lk + 0][lm] = bv.x; Bs[lk + 1][lm] = bv.y; Bs[lk + 2][lm] = bv.z; Bs[lk + 3][lm] = bv.w;
    __syncthreads();
#pragma unroll
    for (int kk = 0; kk < 16; ++kk) {
      float4 a4 = *(const float4*)&As[kk][ty * 4];
      float4 b4 = *(const float4*)&Bs[kk][tx * 4];
      acc[0][0] += a4.x * b4.x; acc[0][1] += a4.x * b4.y; acc[0][2] += a4.x * b4.z; acc[0][3] += a4.x * b4.w;
      acc[1][0] += a4.y * b4.x; acc[1][1] += a4.y * b4.y; acc[1][2] += a4.y * b4.z; acc[1][3] += a4.y * b4.w;
      acc[2][0] += a4.z * b4.x; acc[2][1] += a4.z * b4.y; acc[2][2] += a4.z * b4.z; acc[2][3] += a4.z * b4.w;
      acc[3][0] += a4.w * b4.x; acc[3][1] += a4.w * b4.y; acc[3][2] += a4.w * b4.z; acc[3][3] += a4.w * b4.w;
    }
    __syncthreads();
  }
#pragma unroll
  for (int i = 0; i < 4; ++i) {
#pragma unroll
    for (int j = 0; j < 4; ++j) {
      int gm = bm + ty * 4 + i, gn = bn + tx * 4 + j;
      C[(size_t)gm * ldc + gn] = acc[i][j] + bias[gn];
    }
  }
}

// ---------------- encoder recurrence: self-validating packets + gi prefetch ----------------
__global__ __launch_bounds__(256) void enc_rnn(const float* __restrict__ Whh,
                                               const float* __restrict__ bhh,
                                               const float* __restrict__ gi,
                                               u64* __restrict__ epk,
                                               float* __restrict__ outs) {
  __shared__ unsigned short Whl[ROWS][1024];  // 24 KB
  __shared__ unsigned h_sh[512];
  __shared__ float h_own[4];
  __shared__ float bh[ROWS];
  __shared__ float ghl[ROWS];
  const int b = blockIdx.x, tid = threadIdx.x;
  const int w = tid >> 6, l = tid & 63;
  const int i0 = b * 4;
  for (int idx = tid; idx < ROWS * 1024; idx += 256) {
    int s = idx >> 10, c = idx & 1023;
    Whl[s][c] = f2bf(Whh[(size_t)grow4(s, i0) * H_ + c]);
  }
  if (tid < ROWS) bh[tid] = bhh[grow4(tid, i0)];
  if (tid < 4) h_own[tid] = 0.f;
  __syncthreads();

  for (int t = 0; t < LM_; ++t) {
    float gr = 0.f, gz = 0.f, gn_ = 0.f;
    if (tid < 4) {
      const float* git = gi + (size_t)t * 3072;
      gr = git[i0 + tid]; gz = git[1024 + i0 + tid]; gn_ = git[2048 + i0 + tid];
    }
    if (t == 0) {
      h_sh[2 * tid] = 0u; h_sh[2 * tid + 1] = 0u;
    } else {
      const u64* pb = epk + (size_t)(t & 1) * 512 + 2 * tid;
      const unsigned g = (unsigned)t;
      u64 q0, q1;
      for (;;) {
        q0 = ld_u64(pb); q1 = ld_u64(pb + 1);
        if ((unsigned)(q0 >> 32) == g && (unsigned)(q1 >> 32) == g) break;
        __builtin_amdgcn_s_sleep(1);
      }
      h_sh[2 * tid] = (unsigned)q0;
      h_sh[2 * tid + 1] = (unsigned)q1;
    }
    __syncthreads();

    for (int s = w; s < ROWS; s += 4) {
      float acc = 0.f;
#pragma unroll
      for (int e = 0; e < 8; ++e) {
        unsigned u = *(const unsigned*)&Whl[s][2 * (e * 64 + l)];
        unsigned hv = h_sh[e * 64 + l];
        acc += bflo(u) * bflo(hv) + bfhi(u) * bfhi(hv);
      }
#pragma unroll
      for (int off = 32; off; off >>= 1) acc += __shfl_xor(acc, off);
      if (l == 0) ghl[s] = acc;
    }
    __syncthreads();
    if (tid < 4) {
      int i = tid, ig = i0 + i;
      float hr = ghl[i] + bh[i], hz = ghl[4 + i] + bh[4 + i], hn = ghl[8 + i] + bh[8 + i];
      float r = 1.f / (1.f + expf(-(gr + hr)));
      float z = 1.f / (1.f + expf(-(gz + hz)));
      float n = tanhf(gn_ + r * hn);
      float hpv = (1.f - z) * n + z * h_own[i];
      h_own[i] = hpv;
      float v0 = __shfl(hpv, 0), v1 = __shfl(hpv, 1);
      float v2 = __shfl(hpv, 2), v3 = __shfl(hpv, 3);
      if (tid == 0) {
        u64 gg = (u64)(unsigned)(t + 1) << 32;
        u64* pb = epk + (size_t)((t + 1) & 1) * 512 + 2 * b;
        st_u64(pb,     gg | (u64)((unsigned)f2bf(v0) | ((unsigned)f2bf(v1) << 16)));
        st_u64(pb + 1, gg | (u64)((unsigned)f2bf(v2) | ((unsigned)f2bf(v3) << 16)));
      }
      outs[(size_t)t * H_ + ig] = hpv;
    }
  }
}

// ---------------- decoder recurrence: 5 barriers/step, speculative a-read under h-poll ----
__global__ __launch_bounds__(256) void dec_rnn(const float* __restrict__ Whh,
                                               const float* __restrict__ bhh,
                                               const float* __restrict__ attn_W,
                                               const float* __restrict__ G,
                                               const float* __restrict__ P1,
                                               const float* __restrict__ aE,
                                               const float* __restrict__ hfin,
                                               float* __restrict__ a_acc,
                                               u64* __restrict__ dpk,
                                               unsigned* __restrict__ dflags,
                                               unsigned short* __restrict__ Hs) {
  __shared__ unsigned short Whl[ROWS][1024];  // 24 KB
  __shared__ unsigned Ac[2 * 128];            // 1 KB
  __shared__ float Gl[ROWS][128];             // 6 KB
  __shared__ unsigned h_sh[512];              // 2 KB
  __shared__ float a_f[128];
  __shared__ float h_own[4];
  __shared__ float bh[ROWS];
  __shared__ float ghl[ROWS];
  __shared__ float giS[ROWS];
  const int b = blockIdx.x, tid = threadIdx.x;
  const int w = tid >> 6, l = tid & 63;
  const int i0 = b * 4;
  for (int idx = tid; idx < ROWS * 1024; idx += 256) {
    int s = idx >> 10, c = idx & 1023;
    Whl[s][c] = f2bf(Whh[(size_t)grow4(s, i0) * H_ + c]);
  }
  if (tid < 256) {
    int u = tid >> 7, j = tid & 127;
    float2 wv = *(const float2*)&attn_W[(size_t)j * 2048 + 1024 + i0 + 2 * u];
    Ac[tid] = (unsigned)f2bf(wv.x) | ((unsigned)f2bf(wv.y) << 16);
  }
  for (int idx = tid; idx < ROWS * 128; idx += 256) {
    int s = idx >> 7, c = idx & 127;
    Gl[s][c] = G[(size_t)grow4(s, i0) * 128 + c];
  }
  if (tid < ROWS) bh[tid] = bhh[grow4(tid, i0)];
  if (tid < 4) h_own[tid] = hfin[i0 + tid];   // exact f32 encoder-final h
  __syncthreads();

  // prologue: a-partial adds for t=0 from own h0 chunk, then a-flag = 1
  {
    float h0 = h_own[0], h1 = h_own[1], h2 = h_own[2], h3 = h_own[3];
    if (tid < 128) {
      unsigned w0 = Ac[tid], w1 = Ac[128 + tid];
      float a0 = bflo(w0) * h0 + bfhi(w0) * h1 + bflo(w1) * h2 + bfhi(w1) * h3;
      atom_add_f32(&a_acc[(b & (AREP - 1)) * 128 + tid], a0);
    }
    __syncthreads();  // drain atomics
    if (tid == 0) st_u32(&dflags[b * 16], 1u);
  }

  for (int t = 0; t < LC_; ++t) {
    // ---- wave0: flag check (one-shot in steady state) + issue a_acc/aE loads ----
    u64 aacc[16]; u64 aEv = 0;
    if (tid < 64) {
      const unsigned need = (unsigned)(t + 1);
      for (;;) {
        unsigned f0 = ld_u32(&dflags[tid * 16]);
        unsigned f1 = ld_u32(&dflags[(tid + 64) * 16]);
        unsigned f2 = ld_u32(&dflags[(tid + 128) * 16]);
        unsigned f3 = ld_u32(&dflags[(tid + 192) * 16]);
        unsigned mn = min(min(f0, f1), min(f2, f3));
        if (__all((int)(mn >= need))) break;
        __builtin_amdgcn_s_sleep(1);
      }
      const u64* ab = (const u64*)(a_acc + (size_t)t * (AREP * 128)) + l;
#pragma unroll
      for (int r = 0; r < AREP; ++r) aacc[r] = ld_u64(ab + r * 64);
      float2 ae2 = *(const float2*)&aE[(size_t)t * LM_ + 2 * l];
      aEv = ((u64)__float_as_uint(ae2.y) << 32) | (u64)__float_as_uint(ae2.x);
    }
    // ---- prefetch P1 (independent of h) ----
    float p1p[3];
    if (l == 0) {
#pragma unroll
      for (int k = 0; k < 3; ++k) p1p[k] = P1[(size_t)t * 3072 + grow4(w + 4 * k, i0)];
    } else {
      p1p[0] = p1p[1] = p1p[2] = 0.f;
    }
    // ---- h arrival: self-validating packet poll (t=0: hfin) ----
    if (t == 0) {
      float4 hv = ((const float4*)hfin)[tid];
      h_sh[2 * tid] = (unsigned)f2bf(hv.x) | ((unsigned)f2bf(hv.y) << 16);
      h_sh[2 * tid + 1] = (unsigned)f2bf(hv.z) | ((unsigned)f2bf(hv.w) << 16);
    } else {
      const u64* pb = dpk + (size_t)(t & 1) * 512 + 2 * tid;
      const unsigned g = (unsigned)t;
      u64 q0, q1;
      for (;;) {
        q0 = ld_u64(pb); q1 = ld_u64(pb + 1);
        if ((unsigned)(q0 >> 32) == g && (unsigned)(q1 >> 32) == g) break;
        __builtin_amdgcn_s_sleep(1);
      }
      h_sh[2 * tid] = (unsigned)q0;
      h_sh[2 * tid + 1] = (unsigned)q1;
    }
    __syncthreads();  // B1

    // ---- wave0: finish a_f from in-flight loads; all: gh rows ----
    if (tid < 64) {
      float s0 = 0.f, s1 = 0.f;
#pragma unroll
      for (int r = 0; r < AREP; ++r) {
        s0 += __uint_as_float((unsigned)aacc[r]);
        s1 += __uint_as_float((unsigned)(aacc[r] >> 32));
      }
      a_f[2 * l] = s0 + __uint_as_float((unsigned)aEv);
      a_f[2 * l + 1] = s1 + __uint_as_float((unsigned)(aEv >> 32));
    }
    for (int s = w; s < ROWS; s += 4) {
      float acc = 0.f;
#pragma unroll
      for (int e = 0; e < 8; ++e) {
        unsigned u = *(const unsigned*)&Whl[s][2 * (e * 64 + l)];
        unsigned hv = h_sh[e * 64 + l];
        acc += bflo(u) * bflo(hv) + bfhi(u) * bfhi(hv);
      }
#pragma unroll
      for (int off = 32; off; off >>= 1) acc += __shfl_xor(acc, off);
      if (l == 0) ghl[s] = acc;
    }
    __syncthreads();  // B2

    // ---- softmax over a[128] (per-wave redundant) + gi = P1 + G.w ----
    float ax = a_f[2 * l], ay = a_f[2 * l + 1];
    float mx = fmaxf(ax, ay);
#pragma unroll
    for (int off = 32; off; off >>= 1) mx = fmaxf(mx, __shfl_xor(mx, off));
    float pe0 = expf(ax - mx), pe1 = expf(ay - mx);
    float zs = pe0 + pe1;
#pragma unroll
    for (int off = 32; off; off >>= 1) zs += __shfl_xor(zs, off);
    float w0 = pe0 / zs, w1 = pe1 / zs;
#pragma unroll
    for (int k = 0; k < 3; ++k) {
      int s = w + 4 * k;
      float2 g2 = *(const float2*)&Gl[s][2 * l];
      float acc = g2.x * w0 + g2.y * w1;
#pragma unroll
      for (int off = 32; off; off >>= 1) acc += __shfl_xor(acc, off);
      if (l == 0) giS[s] = acc + p1p[k];
    }
    __syncthreads();  // B3

    // ---- gates + h-packet publish ----
    if (tid < 4) {
      int i = tid, ig = i0 + i;
      float hr = ghl[i] + bh[i], hz = ghl[4 + i] + bh[4 + i], hn = ghl[8 + i] + bh[8 + i];
      float r = 1.f / (1.f + expf(-(giS[i] + hr)));
      float z = 1.f / (1.f + expf(-(giS[4 + i] + hz)));
      float n = tanhf(giS[8 + i] + r * hn);
      float hpv = (1.f - z) * n + z * h_own[i];
      h_own[i] = hpv;
      float v0 = __shfl(hpv, 0), v1 = __shfl(hpv, 1);
      float v2 = __shfl(hpv, 2), v3 = __shfl(hpv, 3);
      if (tid == 0 && t < LC_ - 1) {
        u64 gg = (u64)(unsigned)(t + 1) << 32;
        u64* pb = dpk + (size_t)((t + 1) & 1) * 512 + 2 * b;
        st_u64(pb,     gg | (u64)((unsigned)f2bf(v0) | ((unsigned)f2bf(v1) << 16)));
        st_u64(pb + 1, gg | (u64)((unsigned)f2bf(v2) | ((unsigned)f2bf(v3) << 16)));
      }
      Hs[(size_t)t * H_ + ig] = f2bf(hpv);
    }
    __syncthreads();  // B4: h_own visible

    // ---- a-partial atomics for t+1 (replica b&15), then flag ----
    if (t < LC_ - 1) {
      float h0 = h_own[0], h1 = h_own[1], h2 = h_own[2], h3 = h_own[3];
      if (tid < 128) {
        unsigned w0p = Ac[tid], w1p = Ac[128 + tid];
        float a0 = bflo(w0p) * h0 + bfhi(w0p) * h1 + bflo(w1p) * h2 + bfhi(w1p) * h3;
        atom_add_f32(&a_acc[(size_t)(t + 1) * (AREP * 128) + (b & (AREP - 1)) * 128 + tid], a0);
      }
    }
    __syncthreads();  // B5: drain atomics
    if (tid == 0) st_u32(&dflags[b * 16], (unsigned)(t + 2));
  }
}

// ---------------- MFMA GEMM (double-buffered) + fused softmax partials ----------------
__global__ __launch_bounds__(256) void out_gemm(const unsigned short* __restrict__ A,
                                                const float* __restrict__ Wf, int ldw,
                                                const float* __restrict__ bias,
                                                float* __restrict__ C,
                                                float* __restrict__ pmax,
                                                float* __restrict__ psum,
                                                int N, int K) {
  __shared__ unsigned short As[2][256][40];
  __shared__ unsigned short Bs[2][64][40];
  const int bn = blockIdx.x * 64, bx = blockIdx.x;
  const int tid = threadIdx.x, w = tid >> 6, l = tid & 63;
  const int NIT = K / 32;
  f32x4 acc[4][4];
#pragma unroll
  for (int mf = 0; mf < 4; ++mf)
#pragma unroll
    for (int nf = 0; nf < 4; ++nf) acc[mf][nf] = (f32x4){0.f, 0.f, 0.f, 0.f};

  const int bn_r0 = (tid) >> 3, bkc0 = tid & 7;
  const int bn_r1 = (tid + 256) >> 3, bkc1 = (tid + 256) & 7;

  short8 ar[4];
  float4 fv[2];
  // prologue: load iter 0
  {
    const unsigned short* src = A + (size_t)tid * K;
#pragma unroll
    for (int kc = 0; kc < 4; ++kc) ar[kc] = *(const short8*)(src + kc * 8);
    int gn0 = bn + bn_r0, gn1 = bn + bn_r1;
    fv[0] = (gn0 < N) ? *(const float4*)&Wf[(size_t)gn0 * ldw + bkc0 * 4] : (float4){0, 0, 0, 0};
    fv[1] = (gn1 < N) ? *(const float4*)&Wf[(size_t)gn1 * ldw + bkc1 * 4] : (float4){0, 0, 0, 0};
#pragma unroll
    for (int kc = 0; kc < 4; ++kc) *(short8*)&As[0][tid][kc * 8] = ar[kc];
    uint2 p0, p1;
    p0.x = (unsigned)f2bf(fv[0].x) | ((unsigned)f2bf(fv[0].y) << 16);
    p0.y = (unsigned)f2bf(fv[0].z) | ((unsigned)f2bf(fv[0].w) << 16);
    p1.x = (unsigned)f2bf(fv[1].x) | ((unsigned)f2bf(fv[1].y) << 16);
    p1.y = (unsigned)f2bf(fv[1].z) | ((unsigned)f2bf(fv[1].w) << 16);
    *(uint2*)&Bs[0][bn_r0][bkc0 * 4] = p0;
    *(uint2*)&Bs[0][bn_r1][bkc1 * 4] = p1;
  }

  for (int it = 0; it < NIT; ++it) {
    const int cur = it & 1, nxt = cur ^ 1;
    __syncthreads();
    if (it + 1 < NIT) {
      int k0n = (it + 1) * 32;
      const unsigned short* src = A + (size_t)tid * K + k0n;
#pragma unroll
      for (int kc = 0; kc < 4; ++kc) ar[kc] = *(const short8*)(src + kc * 8);
      int gn0 = bn + bn_r0, gn1 = bn + bn_r1;
      fv[0] = (gn0 < N) ? *(const float4*)&Wf[(size_t)gn0 * ldw + k0n + bkc0 * 4] : (float4){0, 0, 0, 0};
      fv[1] = (gn1 < N) ? *(const float4*)&Wf[(size_t)gn1 * ldw + k0n + bkc1 * 4] : (float4){0, 0, 0, 0};
    }
    const int k8 = (l >> 4) * 8;
    short8 af4[4], bf4[4];
#pragma unroll
    for (int mf = 0; mf < 4; ++mf) af4[mf] = *(const short8*)&As[cur][w * 64 + mf * 16 + (l & 15)][k8];
#pragma unroll
    for (int nf = 0; nf < 4; ++nf) bf4[nf] = *(const short8*)&Bs[cur][nf * 16 + (l & 15)][k8];
#pragma unroll
    for (int mf = 0; mf < 4; ++mf)
#pragma unroll
      for (int nf = 0; nf < 4; ++nf)
        acc[mf][nf] = __builtin_amdgcn_mfma_f32_16x16x32_bf16(af4[mf], bf4[nf], acc[mf][nf], 0, 0, 0);
    if (it + 1 < NIT) {
#pragma unroll
      for (int kc = 0; kc < 4; ++kc) *(short8*)&As[nxt][tid][kc * 8] = ar[kc];
      uint2 p0, p1;
      p0.x = (unsigned)f2bf(fv[0].x) | ((unsigned)f2bf(fv[0].y) << 16);
      p0.y = (unsigned)f2bf(fv[0].z) | ((unsigned)f2bf(fv[0].w) << 16);
      p1.x = (unsigned)f2bf(fv[1].x) | ((unsigned)f2bf(fv[1].y) << 16);
      p1.y = (unsigned)f2bf(fv[1].z) | ((unsigned)f2bf(fv[1].w) << 16);
      *(uint2*)&Bs[nxt][bn_r0][bkc0 * 4] = p0;
      *(uint2*)&Bs[nxt][bn_r1][bkc1 * 4] = p1;
    }
  }
#pragma unroll
  for (int mf = 0; mf < 4; ++mf) {
#pragma unroll
    for (int i = 0; i < 4; ++i) {
      int m = w * 64 + mf * 16 + (l >> 4) * 4 + i;
      float v[4];
#pragma unroll
      for (int nf = 0; nf < 4; ++nf) {
        int n = bn + nf * 16 + (l & 15);
        float val = -3.4e38f;
        if (n < N) {
          val = acc[mf][nf][i] + bias[n];
          C[(size_t)m * N + n] = val;
        }
        v[nf] = val;
      }
      float mv = fmaxf(fmaxf(v[0], v[1]), fmaxf(v[2], v[3]));
#pragma unroll
      for (int off = 1; off < 16; off <<= 1) mv = fmaxf(mv, __shfl_xor(mv, off));
      float se = 0.f;
#pragma unroll
      for (int nf = 0; nf < 4; ++nf) se += (v[nf] > -1e38f) ? expf(v[nf] - mv) : 0.f;
#pragma unroll
      for (int off = 1; off < 16; off <<= 1) se += __shfl_xor(se, off);
      if ((l & 15) == 0) {
        pmax[(size_t)m * NT_OUT + bx] = mv;
        psum[(size_t)m * NT_OUT + bx] = se;
      }
    }
  }
}

// ---------------- combine partials -> stats ----------------
__global__ __launch_bounds__(256) void lsm_combine(const float* __restrict__ pmax,
                                                   const float* __restrict__ psum,
                                                   float* __restrict__ stats) {
  const int r = blockIdx.x, tid = threadIdx.x, w = tid >> 6, l = tid & 63;
  __shared__ float red[4];
  __shared__ float Msh;
  const float* pm = pmax + (size_t)r * NT_OUT;
  const float* ps = psum + (size_t)r * NT_OUT;
  float m = -3.4e38f;
  for (int j = tid; j < NT_OUT; j += 256) m = fmaxf(m, pm[j]);
#pragma unroll
  for (int off = 32; off; off >>= 1) m = fmaxf(m, __shfl_xor(m, off));
  if (l == 0) red[w] = m;
  __syncthreads();
  if (tid == 0) Msh = fmaxf(fmaxf(red[0], red[1]), fmaxf(red[2], red[3]));
  __syncthreads();
  float M = Msh;
  float s = 0.f;
  for (int j = tid; j < NT_OUT; j += 256) s += ps[j] * expf(pm[j] - M);
#pragma unroll
  for (int off = 32; off; off >>= 1) s += __shfl_xor(s, off);
  if (l == 0) red[w] = s;
  __syncthreads();
  if (tid == 0) {
    stats[r] = M;
    stats[256 + r] = logf(red[0] + red[1] + red[2] + red[3]);
  }
}

__global__ __launch_bounds__(256) void lsm_apply(float* __restrict__ C, const float* __restrict__ stats, int N) {
  int r = blockIdx.y;
  int ci = blockIdx.x * 256 + threadIdx.x;
  if (ci < N) {
    size_t idx = (size_t)r * N + ci;
    C[idx] = C[idx] - stats[r] - stats[256 + r];
  }
}

extern "C" void kernel_launch(void* const* d_in, const int* in_sizes, int n_in,
                              void* d_out, int out_size, void* d_ws, size_t ws_size,
                              hipStream_t stream) {
  (void)in_sizes; (void)n_in; (void)out_size; (void)ws_size;
  const int* motion = (const int*)d_in[0];
  const int* tgt = (const int*)d_in[1];
  const float* enc_emb = (const float*)d_in[2];
  const float* enc_Wih = (const float*)d_in[3];
  const float* enc_Whh = (const float*)d_in[4];
  const float* enc_bih = (const float*)d_in[5];
  const float* enc_bhh = (const float*)d_in[6];
  const float* dec_emb = (const float*)d_in[7];
  const float* dec_Wih = (const float*)d_in[8];
  const float* dec_Whh = (const float*)d_in[9];
  const float* dec_bih = (const float*)d_in[10];
  const float* dec_bhh = (const float*)d_in[11];
  const float* attn_W = (const float*)d_in[12];
  const float* attn_b = (const float*)d_in[13];
  const float* comb_W = (const float*)d_in[14];
  const float* comb_b = (const float*)d_in[15];
  const float* out_W = (const float*)d_in[16];
  const float* out_b = (const float*)d_in[17];
  float* out = (float*)d_out;

  // workspace layout (floats, 16B-aligned chunks)
  float* wsf = (float*)d_ws;
  size_t o = 0;
  auto F = [&](size_t n) { float* p = wsf + o; o += (n + 3) & ~(size_t)3; return p; };
  float* enc_gi = F(128 * 3072);
  float* enc_outs = F(128 * 1024);
  float* aE = F(256 * 128);
  float* xE = F(256 * 1024);
  float* P1 = F(256 * 3072);
  float* M2T = F(128 * 1024);
  float* Gm = F(3072 * 128);
  int* dec_tok = (int*)F(256);
  u64* epk = (u64*)F(2048);                   // [2][256][2] u64 packets  } contiguous
  u64* dpk = (u64*)F(2048);                   //                          } for single
  unsigned* dflags = (unsigned*)F(4096);      // 256 flags, 64B apart     } memset
  float* a_acc = F(LC_ * AREP * 128);         // per-step 16-replica a accumulators
  float* stats = F(512);
  float* pmax = F(256 * NT_OUT);
  float* psum = F(256 * NT_OUT);
  unsigned short* Hs = (unsigned short*)F(256 * 1024 / 2);

  // fresh packets/flags/accumulators each launch (epk..a_acc contiguous)
  hipMemsetAsync(epk, 0, (2048 + 2048 + 4096 + LC_ * AREP * 128) * sizeof(float), stream);

  // precompute (gather-fused GEMMs)
  build_dec_tok<<<1, 256, 0, stream>>>(tgt, dec_tok);
  gemm_g<<<dim3(48, 2), 256, 0, stream>>>(enc_emb, 512, motion, enc_Wih, 512, enc_bih, enc_gi, 3072, 512);
  gemm_dual<<<dim3(18, 4), 256, 0, stream>>>(dec_emb, 1024, dec_tok, comb_W, comb_b, attn_W, attn_b, xE, aE, 1024);
  gemm_g<<<dim3(48, 4), 256, 0, stream>>>(xE, 1024, nullptr, dec_Wih, 1024, dec_bih, P1, 3072, 1024);

  // encoder recurrence
  enc_rnn<<<NBLK, 256, 0, stream>>>(enc_Whh, enc_bhh, enc_gi, epk, enc_outs);

  // G = dec_Wih @ (comb_W[:,H:] @ enc_outs^T)
  gemm_g<<<dim3(16, 2), 256, 0, stream>>>(enc_outs, 1024, nullptr, comb_W + 1024, 2048, nullptr, M2T, 1024, 1024);
  gemm_g<<<dim3(2, 48), 256, 0, stream>>>(dec_Wih, 1024, nullptr, M2T, 1024, nullptr, Gm, 128, 1024);

  // decoder recurrence
  dec_rnn<<<NBLK, 256, 0, stream>>>(dec_Whh, dec_bhh, attn_W, Gm, P1, aE,
                                    enc_outs + (size_t)(LM_ - 1) * H_, a_acc, dpk, dflags, Hs);

  // output projection (+ fused softmax partials) + combine + apply
  out_gemm<<<NT_OUT, 256, 0, stream>>>(Hs, out_W, 1024, out_b, out, pmax, psum, V_, 1024);
  lsm_combine<<<256, 256, 0, stream>>>(pmax, psum, stats);
  lsm_apply<<<dim3(197, 256), 256, 0, stream>>>(out, stats, V_);
}

// Round 15
// 2328.386 us; speedup vs baseline: 1.0738x; 1.0020x over previous
//
#include <hip/hip_runtime.h>

// Problem dims
#define V_ 50257
#define E_ 512
#define H_ 1024
#define LM_ 128
#define LC_ 256
#define NBLK 256   // recurrence blocks: 1 per CU, 4 h-outputs each
#define ROWS 12    // 3 gates x 4 outputs
#define AREP 16    // a-accumulator replicas (contention divisor)
#define HREP 8     // h-packet array replicas (poll-contention divisor)
#define FREP 4     // dflags replicas
#define NT_OUT 786 // out_gemm col-tiles

typedef __attribute__((ext_vector_type(8))) short short8;
typedef __attribute__((ext_vector_type(4))) float f32x4;
typedef unsigned long long u64;

__device__ __forceinline__ unsigned short f2bf(float x) {
  union { float f; unsigned u; } v; v.f = x;
  unsigned r = v.u + 0x7fffu + ((v.u >> 16) & 1u);   // round-to-nearest-even
  return (unsigned short)(r >> 16);
}
__device__ __forceinline__ float bflo(unsigned u) { union { unsigned u; float f; } v; v.u = u << 16; return v.f; }
__device__ __forceinline__ float bfhi(unsigned u) { union { unsigned u; float f; } v; v.u = u & 0xffff0000u; return v.f; }

__device__ __forceinline__ int grow4(int s, int i0) {
  return (s < 4) ? (i0 + s) : (s < 8) ? (1024 + i0 + (s - 4)) : (2048 + i0 + (s - 8));
}

// relaxed agent-scope ops (served at coherence point; no fences -> no L2 flush/inv)
__device__ __forceinline__ void st_u32(unsigned* p, unsigned v) {
  __hip_atomic_store(p, v, __ATOMIC_RELAXED, __HIP_MEMORY_SCOPE_AGENT);
}
__device__ __forceinline__ void st_u64(u64* p, u64 v) {
  __hip_atomic_store(p, v, __ATOMIC_RELAXED, __HIP_MEMORY_SCOPE_AGENT);
}
__device__ __forceinline__ u64 ld_u64(const u64* p) {
  return __hip_atomic_load(p, __ATOMIC_RELAXED, __HIP_MEMORY_SCOPE_AGENT);
}
__device__ __forceinline__ unsigned ld_u32(const unsigned* p) {
  return __hip_atomic_load(p, __ATOMIC_RELAXED, __HIP_MEMORY_SCOPE_AGENT);
}
__device__ __forceinline__ void atom_add_f32(float* p, float v) {
  (void)__hip_atomic_fetch_add(p, v, __ATOMIC_RELAXED, __HIP_MEMORY_SCOPE_AGENT);
}

// ---------------- decoder token table ----------------
__global__ void build_dec_tok(const int* __restrict__ tgt, int* __restrict__ dtok) {
  int t = threadIdx.x;
  dtok[t] = (t == 0) ? 0 : (t == 1 ? tgt[LC_ - 1] : tgt[t - 2]);
}

// ---------------- gathered f32 GEMM: C[M,N] = A[rows][K] @ B[N,K]^T + bias ----------------
__global__ __launch_bounds__(256) void gemm_g(const float* __restrict__ A, int lda,
                                              const int* __restrict__ ridx,
                                              const float* __restrict__ B, int ldb,
                                              const float* __restrict__ bias,
                                              float* __restrict__ C, int ldc, int K) {
  __shared__ float As[16][68];
  __shared__ float Bs[16][68];
  const int bm = blockIdx.y * 64, bn = blockIdx.x * 64;
  const int tid = threadIdx.x;
  const int tx = tid & 15, ty = tid >> 4;
  const int lm = tid & 63, lk = (tid >> 6) * 4;
  const int arow = ridx ? ridx[bm + lm] : (bm + lm);
  const float* Arow = A + (size_t)arow * lda;
  float acc[4][4] = {};
  for (int k0 = 0; k0 < K; k0 += 16) {
    float4 av = *(const float4*)&Arow[k0 + lk];
    float4 bv = *(const float4*)&B[(size_t)(bn + lm) * ldb + k0 + lk];
    As[lk + 0][lm] = av.x; As[lk + 1][lm] = av.y; As[lk + 2][lm] = av.z; As[lk + 3][lm] = av.w;
    Bs[lk + 0][lm] = bv.x; Bs[lk + 1][lm] = bv.y; Bs[lk + 2][lm] = bv.z; Bs[lk + 3][lm] = bv.w;
    __syncthreads();
#pragma unroll
    for (int kk = 0; kk < 16; ++kk) {
      float4 a4 = *(const float4*)&As[kk][ty * 4];
      float4 b4 = *(const float4*)&Bs[kk][tx * 4];
      acc[0][0] += a4.x * b4.x; acc[0][1] += a4.x * b4.y; acc[0][2] += a4.x * b4.z; acc[0][3] += a4.x * b4.w;
      acc[1][0] += a4.y * b4.x; acc[1][1] += a4.y * b4.y; acc[1][2] += a4.y * b4.z; acc[1][3] += a4.y * b4.w;
      acc[2][0] += a4.z * b4.x; acc[2][1] += a4.z * b4.y; acc[2][2] += a4.z * b4.z; acc[2][3] += a4.z * b4.w;
      acc[3][0] += a4.w * b4.x; acc[3][1] += a4.w * b4.y; acc[3][2] += a4.w * b4.z; acc[3][3] += a4.w * b4.w;
    }
    __syncthreads();
  }
#pragma unroll
  for (int i = 0; i < 4; ++i) {
#pragma unroll
    for (int j = 0; j < 4; ++j) {
      int gm = bm + ty * 4 + i, gn = bn + tx * 4 + j;
      float bv = bias ? bias[gn] : 0.f;
      C[(size_t)gm * ldc + gn] = acc[i][j] + bv;
    }
  }
}

// ---------------- dual-output gathered GEMM: xE (bx<16) and aE (bx>=16) from dec_emb ----
__global__ __launch_bounds__(256) void gemm_dual(const float* __restrict__ A, int lda,
                                                 const int* __restrict__ ridx,
                                                 const float* __restrict__ combW,
                                                 const float* __restrict__ comb_b,
                                                 const float* __restrict__ attnW,
                                                 const float* __restrict__ attn_b,
                                                 float* __restrict__ xE,
                                                 float* __restrict__ aE, int K) {
  __shared__ float As[16][68];
  __shared__ float Bs[16][68];
  const int bm = blockIdx.y * 64;
  const bool is_x = blockIdx.x < 16;
  const int bn = (is_x ? blockIdx.x : (blockIdx.x - 16)) * 64;
  const float* B = is_x ? combW : attnW;
  const int ldb = 2048;
  const float* bias = is_x ? comb_b : attn_b;
  float* C = is_x ? xE : aE;
  const int ldc = is_x ? 1024 : 128;
  const int tid = threadIdx.x;
  const int tx = tid & 15, ty = tid >> 4;
  const int lm = tid & 63, lk = (tid >> 6) * 4;
  const int arow = ridx[bm + lm];
  const float* Arow = A + (size_t)arow * lda;
  float acc[4][4] = {};
  for (int k0 = 0; k0 < K; k0 += 16) {
    float4 av = *(const float4*)&Arow[k0 + lk];
    float4 bv = *(const float4*)&B[(size_t)(bn + lm) * ldb + k0 + lk];
    As[lk + 0][lm] = av.x; As[lk + 1][lm] = av.y; As[lk + 2][lm] = av.z; As[lk + 3][lm] = av.w;
    Bs[lk + 0][lm] = bv.x; Bs[lk + 1][lm] = bv.y; Bs[lk + 2][lm] = bv.z; Bs[lk + 3][lm] = bv.w;
    __syncthreads();
#pragma unroll
    for (int kk = 0; kk < 16; ++kk) {
      float4 a4 = *(const float4*)&As[kk][ty * 4];
      float4 b4 = *(const float4*)&Bs[kk][tx * 4];
      acc[0][0] += a4.x * b4.x; acc[0][1] += a4.x * b4.y; acc[0][2] += a4.x * b4.z; acc[0][3] += a4.x * b4.w;
      acc[1][0] += a4.y * b4.x; acc[1][1] += a4.y * b4.y; acc[1][2] += a4.y * b4.z; acc[1][3] += a4.y * b4.w;
      acc[2][0] += a4.z * b4.x; acc[2][1] += a4.z * b4.y; acc[2][2] += a4.z * b4.z; acc[2][3] += a4.z * b4.w;
      acc[3][0] += a4.w * b4.x; acc[3][1] += a4.w * b4.y; acc[3][2] += a4.w * b4.z; acc[3][3] += a4.w * b4.w;
    }
    __syncthreads();
  }
#pragma unroll
  for (int i = 0; i < 4; ++i) {
#pragma unroll
    for (int j = 0; j < 4; ++j) {
      int gm = bm + ty * 4 + i, gn = bn + tx * 4 + j;
      C[(size_t)gm * ldc + gn] = acc[i][j] + bias[gn];
    }
  }
}

// ---------------- encoder recurrence: 8x-replicated self-validating packets ----------------
// epk[rep][2][512] u64. Block b polls replica b&7; publisher writes all HREP replicas.
__global__ __launch_bounds__(256) void enc_rnn(const float* __restrict__ Whh,
                                               const float* __restrict__ bhh,
                                               const float* __restrict__ gi,
                                               u64* __restrict__ epk,
                                               float* __restrict__ outs) {
  __shared__ unsigned short Whl[ROWS][1024];  // 24 KB
  __shared__ unsigned h_sh[512];
  __shared__ float h_own[4];
  __shared__ float bh[ROWS];
  __shared__ float ghl[ROWS];
  const int b = blockIdx.x, tid = threadIdx.x;
  const int w = tid >> 6, l = tid & 63;
  const int i0 = b * 4;
  const u64* myrep = epk + (size_t)(b & (HREP - 1)) * 1024;
  for (int idx = tid; idx < ROWS * 1024; idx += 256) {
    int s = idx >> 10, c = idx & 1023;
    Whl[s][c] = f2bf(Whh[(size_t)grow4(s, i0) * H_ + c]);
  }
  if (tid < ROWS) bh[tid] = bhh[grow4(tid, i0)];
  if (tid < 4) h_own[tid] = 0.f;
  __syncthreads();

  for (int t = 0; t < LM_; ++t) {
    float gr = 0.f, gz = 0.f, gn_ = 0.f;
    if (tid < 4) {
      const float* git = gi + (size_t)t * 3072;
      gr = git[i0 + tid]; gz = git[1024 + i0 + tid]; gn_ = git[2048 + i0 + tid];
    }
    if (t == 0) {
      h_sh[2 * tid] = 0u; h_sh[2 * tid + 1] = 0u;
    } else {
      const u64* pb = myrep + (size_t)(t & 1) * 512 + 2 * tid;
      const unsigned g = (unsigned)t;
      u64 q0, q1;
      for (;;) {
        q0 = ld_u64(pb); q1 = ld_u64(pb + 1);
        if ((unsigned)(q0 >> 32) == g && (unsigned)(q1 >> 32) == g) break;
        __builtin_amdgcn_s_sleep(1);
      }
      h_sh[2 * tid] = (unsigned)q0;
      h_sh[2 * tid + 1] = (unsigned)q1;
    }
    __syncthreads();

    for (int s = w; s < ROWS; s += 4) {
      float acc = 0.f;
#pragma unroll
      for (int e = 0; e < 8; ++e) {
        unsigned u = *(const unsigned*)&Whl[s][2 * (e * 64 + l)];
        unsigned hv = h_sh[e * 64 + l];
        acc += bflo(u) * bflo(hv) + bfhi(u) * bfhi(hv);
      }
#pragma unroll
      for (int off = 32; off; off >>= 1) acc += __shfl_xor(acc, off);
      if (l == 0) ghl[s] = acc;
    }
    __syncthreads();
    if (tid < 4) {
      int i = tid, ig = i0 + i;
      float hr = ghl[i] + bh[i], hz = ghl[4 + i] + bh[4 + i], hn = ghl[8 + i] + bh[8 + i];
      float r = 1.f / (1.f + expf(-(gr + hr)));
      float z = 1.f / (1.f + expf(-(gz + hz)));
      float n = tanhf(gn_ + r * hn);
      float hpv = (1.f - z) * n + z * h_own[i];
      h_own[i] = hpv;
      float v0 = __shfl(hpv, 0), v1 = __shfl(hpv, 1);
      float v2 = __shfl(hpv, 2), v3 = __shfl(hpv, 3);
      if (tid == 0) {
        u64 gg = (u64)(unsigned)(t + 1) << 32;
        u64 p0 = gg | (u64)((unsigned)f2bf(v0) | ((unsigned)f2bf(v1) << 16));
        u64 p1 = gg | (u64)((unsigned)f2bf(v2) | ((unsigned)f2bf(v3) << 16));
        size_t slot = (size_t)((t + 1) & 1) * 512 + 2 * b;
#pragma unroll
        for (int r2 = 0; r2 < HREP; ++r2) {
          st_u64(epk + (size_t)r2 * 1024 + slot, p0);
          st_u64(epk + (size_t)r2 * 1024 + slot + 1, p1);
        }
      }
      outs[(size_t)t * H_ + ig] = hpv;
    }
  }
}

// ---------------- decoder recurrence: replicated packets/flags, spec a-read under poll ----
__global__ __launch_bounds__(256) void dec_rnn(const float* __restrict__ Whh,
                                               const float* __restrict__ bhh,
                                               const float* __restrict__ attn_W,
                                               const float* __restrict__ G,
                                               const float* __restrict__ P1,
                                               const float* __restrict__ aE,
                                               const float* __restrict__ hfin,
                                               float* __restrict__ a_acc,
                                               u64* __restrict__ dpk,
                                               unsigned* __restrict__ dflags,
                                               unsigned short* __restrict__ Hs) {
  __shared__ unsigned short Whl[ROWS][1024];  // 24 KB
  __shared__ unsigned Ac[2 * 128];            // 1 KB
  __shared__ float Gl[ROWS][128];             // 6 KB
  __shared__ unsigned h_sh[512];              // 2 KB
  __shared__ float a_f[128];
  __shared__ float h_own[4];
  __shared__ float bh[ROWS];
  __shared__ float ghl[ROWS];
  __shared__ float giS[ROWS];
  const int b = blockIdx.x, tid = threadIdx.x;
  const int w = tid >> 6, l = tid & 63;
  const int i0 = b * 4;
  const u64* myrep = dpk + (size_t)(b & (HREP - 1)) * 1024;
  const unsigned* myfl = dflags + (size_t)(b & (FREP - 1)) * 1024;
  for (int idx = tid; idx < ROWS * 1024; idx += 256) {
    int s = idx >> 10, c = idx & 1023;
    Whl[s][c] = f2bf(Whh[(size_t)grow4(s, i0) * H_ + c]);
  }
  if (tid < 256) {
    int u = tid >> 7, j = tid & 127;
    float2 wv = *(const float2*)&attn_W[(size_t)j * 2048 + 1024 + i0 + 2 * u];
    Ac[tid] = (unsigned)f2bf(wv.x) | ((unsigned)f2bf(wv.y) << 16);
  }
  for (int idx = tid; idx < ROWS * 128; idx += 256) {
    int s = idx >> 7, c = idx & 127;
    Gl[s][c] = G[(size_t)grow4(s, i0) * 128 + c];
  }
  if (tid < ROWS) bh[tid] = bhh[grow4(tid, i0)];
  if (tid < 4) h_own[tid] = hfin[i0 + tid];   // exact f32 encoder-final h
  __syncthreads();

  // prologue: a-partial adds for t=0 from own h0 chunk, then a-flag = 1 (all replicas)
  {
    float h0 = h_own[0], h1 = h_own[1], h2 = h_own[2], h3 = h_own[3];
    if (tid < 128) {
      unsigned w0 = Ac[tid], w1 = Ac[128 + tid];
      float a0 = bflo(w0) * h0 + bfhi(w0) * h1 + bflo(w1) * h2 + bfhi(w1) * h3;
      atom_add_f32(&a_acc[(b & (AREP - 1)) * 128 + tid], a0);
    }
    __syncthreads();  // drain atomics
    if (tid == 0) {
#pragma unroll
      for (int r2 = 0; r2 < FREP; ++r2) st_u32(&dflags[(size_t)r2 * 1024 + b * 16], 1u);
    }
  }

  for (int t = 0; t < LC_; ++t) {
    // ---- wave0: flag check (one-shot in steady state) + issue a_acc/aE loads ----
    u64 aacc[16]; u64 aEv = 0;
    if (tid < 64) {
      const unsigned need = (unsigned)(t + 1);
      for (;;) {
        unsigned f0 = ld_u32(&myfl[tid * 16]);
        unsigned f1 = ld_u32(&myfl[(tid + 64) * 16]);
        unsigned f2 = ld_u32(&myfl[(tid + 128) * 16]);
        unsigned f3 = ld_u32(&myfl[(tid + 192) * 16]);
        unsigned mn = min(min(f0, f1), min(f2, f3));
        if (__all((int)(mn >= need))) break;
        __builtin_amdgcn_s_sleep(1);
      }
      const u64* ab = (const u64*)(a_acc + (size_t)t * (AREP * 128)) + l;
#pragma unroll
      for (int r = 0; r < AREP; ++r) aacc[r] = ld_u64(ab + r * 64);
      float2 ae2 = *(const float2*)&aE[(size_t)t * LM_ + 2 * l];
      aEv = ((u64)__float_as_uint(ae2.y) << 32) | (u64)__float_as_uint(ae2.x);
    }
    // ---- prefetch P1 (independent of h) ----
    float p1p[3];
    if (l == 0) {
#pragma unroll
      for (int k = 0; k < 3; ++k) p1p[k] = P1[(size_t)t * 3072 + grow4(w + 4 * k, i0)];
    } else {
      p1p[0] = p1p[1] = p1p[2] = 0.f;
    }
    // ---- h arrival: self-validating packet poll on own replica (t=0: hfin) ----
    if (t == 0) {
      float4 hv = ((const float4*)hfin)[tid];
      h_sh[2 * tid] = (unsigned)f2bf(hv.x) | ((unsigned)f2bf(hv.y) << 16);
      h_sh[2 * tid + 1] = (unsigned)f2bf(hv.z) | ((unsigned)f2bf(hv.w) << 16);
    } else {
      const u64* pb = myrep + (size_t)(t & 1) * 512 + 2 * tid;
      const unsigned g = (unsigned)t;
      u64 q0, q1;
      for (;;) {
        q0 = ld_u64(pb); q1 = ld_u64(pb + 1);
        if ((unsigned)(q0 >> 32) == g && (unsigned)(q1 >> 32) == g) break;
        __builtin_amdgcn_s_sleep(1);
      }
      h_sh[2 * tid] = (unsigned)q0;
      h_sh[2 * tid + 1] = (unsigned)q1;
    }
    __syncthreads();  // B1

    // ---- wave0: finish a_f from in-flight loads; all: gh rows ----
    if (tid < 64) {
      float s0 = 0.f, s1 = 0.f;
#pragma unroll
      for (int r = 0; r < AREP; ++r) {
        s0 += __uint_as_float((unsigned)aacc[r]);
        s1 += __uint_as_float((unsigned)(aacc[r] >> 32));
      }
      a_f[2 * l] = s0 + __uint_as_float((unsigned)aEv);
      a_f[2 * l + 1] = s1 + __uint_as_float((unsigned)(aEv >> 32));
    }
    for (int s = w; s < ROWS; s += 4) {
      float acc = 0.f;
#pragma unroll
      for (int e = 0; e < 8; ++e) {
        unsigned u = *(const unsigned*)&Whl[s][2 * (e * 64 + l)];
        unsigned hv = h_sh[e * 64 + l];
        acc += bflo(u) * bflo(hv) + bfhi(u) * bfhi(hv);
      }
#pragma unroll
      for (int off = 32; off; off >>= 1) acc += __shfl_xor(acc, off);
      if (l == 0) ghl[s] = acc;
    }
    __syncthreads();  // B2

    // ---- softmax over a[128] (per-wave redundant) + gi = P1 + G.w ----
    float ax = a_f[2 * l], ay = a_f[2 * l + 1];
    float mx = fmaxf(ax, ay);
#pragma unroll
    for (int off = 32; off; off >>= 1) mx = fmaxf(mx, __shfl_xor(mx, off));
    float pe0 = expf(ax - mx), pe1 = expf(ay - mx);
    float zs = pe0 + pe1;
#pragma unroll
    for (int off = 32; off; off >>= 1) zs += __shfl_xor(zs, off);
    float w0 = pe0 / zs, w1 = pe1 / zs;
#pragma unroll
    for (int k = 0; k < 3; ++k) {
      int s = w + 4 * k;
      float2 g2 = *(const float2*)&Gl[s][2 * l];
      float acc = g2.x * w0 + g2.y * w1;
#pragma unroll
      for (int off = 32; off; off >>= 1) acc += __shfl_xor(acc, off);
      if (l == 0) giS[s] = acc + p1p[k];
    }
    __syncthreads();  // B3

    // ---- gates + h-packet publish (all replicas) ----
    if (tid < 4) {
      int i = tid, ig = i0 + i;
      float hr = ghl[i] + bh[i], hz = ghl[4 + i] + bh[4 + i], hn = ghl[8 + i] + bh[8 + i];
      float r = 1.f / (1.f + expf(-(giS[i] + hr)));
      float z = 1.f / (1.f + expf(-(giS[4 + i] + hz)));
      float n = tanhf(giS[8 + i] + r * hn);
      float hpv = (1.f - z) * n + z * h_own[i];
      h_own[i] = hpv;
      float v0 = __shfl(hpv, 0), v1 = __shfl(hpv, 1);
      float v2 = __shfl(hpv, 2), v3 = __shfl(hpv, 3);
      if (tid == 0 && t < LC_ - 1) {
        u64 gg = (u64)(unsigned)(t + 1) << 32;
        u64 p0 = gg | (u64)((unsigned)f2bf(v0) | ((unsigned)f2bf(v1) << 16));
        u64 p1 = gg | (u64)((unsigned)f2bf(v2) | ((unsigned)f2bf(v3) << 16));
        size_t slot = (size_t)((t + 1) & 1) * 512 + 2 * b;
#pragma unroll
        for (int r2 = 0; r2 < HREP; ++r2) {
          st_u64(dpk + (size_t)r2 * 1024 + slot, p0);
          st_u64(dpk + (size_t)r2 * 1024 + slot + 1, p1);
        }
      }
      Hs[(size_t)t * H_ + ig] = f2bf(hpv);
    }
    __syncthreads();  // B4: h_own visible

    // ---- a-partial atomics for t+1 (replica b&15), then flags (all replicas) ----
    if (t < LC_ - 1) {
      float h0 = h_own[0], h1 = h_own[1], h2 = h_own[2], h3 = h_own[3];
      if (tid < 128) {
        unsigned w0p = Ac[tid], w1p = Ac[128 + tid];
        float a0 = bflo(w0p) * h0 + bfhi(w0p) * h1 + bflo(w1p) * h2 + bfhi(w1p) * h3;
        atom_add_f32(&a_acc[(size_t)(t + 1) * (AREP * 128) + (b & (AREP - 1)) * 128 + tid], a0);
      }
    }
    __syncthreads();  // B5: drain atomics
    if (tid == 0) {
#pragma unroll
      for (int r2 = 0; r2 < FREP; ++r2) st_u32(&dflags[(size_t)r2 * 1024 + b * 16], (unsigned)(t + 2));
    }
  }
}

// ---------------- MFMA GEMM (double-buffered) + fused softmax partials ----------------
__global__ __launch_bounds__(256) void out_gemm(const unsigned short* __restrict__ A,
                                                const float* __restrict__ Wf, int ldw,
                                                const float* __restrict__ bias,
                                                float* __restrict__ C,
                                                float* __restrict__ pmax,
                                                float* __restrict__ psum,
                                                int N, int K) {
  __shared__ unsigned short As[2][256][40];
  __shared__ unsigned short Bs[2][64][40];
  const int bn = blockIdx.x * 64, bx = blockIdx.x;
  const int tid = threadIdx.x, w = tid >> 6, l = tid & 63;
  const int NIT = K / 32;
  f32x4 acc[4][4];
#pragma unroll
  for (int mf = 0; mf < 4; ++mf)
#pragma unroll
    for (int nf = 0; nf < 4; ++nf) acc[mf][nf] = (f32x4){0.f, 0.f, 0.f, 0.f};

  const int bn_r0 = (tid) >> 3, bkc0 = tid & 7;
  const int bn_r1 = (tid + 256) >> 3, bkc1 = (tid + 256) & 7;

  short8 ar[4];
  float4 fv[2];
  // prologue: load iter 0
  {
    const unsigned short* src = A + (size_t)tid * K;
#pragma unroll
    for (int kc = 0; kc < 4; ++kc) ar[kc] = *(const short8*)(src + kc * 8);
    int gn0 = bn + bn_r0, gn1 = bn + bn_r1;
    fv[0] = (gn0 < N) ? *(const float4*)&Wf[(size_t)gn0 * ldw + bkc0 * 4] : (float4){0, 0, 0, 0};
    fv[1] = (gn1 < N) ? *(const float4*)&Wf[(size_t)gn1 * ldw + bkc1 * 4] : (float4){0, 0, 0, 0};
#pragma unroll
    for (int kc = 0; kc < 4; ++kc) *(short8*)&As[0][tid][kc * 8] = ar[kc];
    uint2 p0, p1;
    p0.x = (unsigned)f2bf(fv[0].x) | ((unsigned)f2bf(fv[0].y) << 16);
    p0.y = (unsigned)f2bf(fv[0].z) | ((unsigned)f2bf(fv[0].w) << 16);
    p1.x = (unsigned)f2bf(fv[1].x) | ((unsigned)f2bf(fv[1].y) << 16);
    p1.y = (unsigned)f2bf(fv[1].z) | ((unsigned)f2bf(fv[1].w) << 16);
    *(uint2*)&Bs[0][bn_r0][bkc0 * 4] = p0;
    *(uint2*)&Bs[0][bn_r1][bkc1 * 4] = p1;
  }

  for (int it = 0; it < NIT; ++it) {
    const int cur = it & 1, nxt = cur ^ 1;
    __syncthreads();
    if (it + 1 < NIT) {
      int k0n = (it + 1) * 32;
      const unsigned short* src = A + (size_t)tid * K + k0n;
#pragma unroll
      for (int kc = 0; kc < 4; ++kc) ar[kc] = *(const short8*)(src + kc * 8);
      int gn0 = bn + bn_r0, gn1 = bn + bn_r1;
      fv[0] = (gn0 < N) ? *(const float4*)&Wf[(size_t)gn0 * ldw + k0n + bkc0 * 4] : (float4){0, 0, 0, 0};
      fv[1] = (gn1 < N) ? *(const float4*)&Wf[(size_t)gn1 * ldw + k0n + bkc1 * 4] : (float4){0, 0, 0, 0};
    }
    const int k8 = (l >> 4) * 8;
    short8 af4[4], bf4[4];
#pragma unroll
    for (int mf = 0; mf < 4; ++mf) af4[mf] = *(const short8*)&As[cur][w * 64 + mf * 16 + (l & 15)][k8];
#pragma unroll
    for (int nf = 0; nf < 4; ++nf) bf4[nf] = *(const short8*)&Bs[cur][nf * 16 + (l & 15)][k8];
#pragma unroll
    for (int mf = 0; mf < 4; ++mf)
#pragma unroll
      for (int nf = 0; nf < 4; ++nf)
        acc[mf][nf] = __builtin_amdgcn_mfma_f32_16x16x32_bf16(af4[mf], bf4[nf], acc[mf][nf], 0, 0, 0);
    if (it + 1 < NIT) {
#pragma unroll
      for (int kc = 0; kc < 4; ++kc) *(short8*)&As[nxt][tid][kc * 8] = ar[kc];
      uint2 p0, p1;
      p0.x = (unsigned)f2bf(fv[0].x) | ((unsigned)f2bf(fv[0].y) << 16);
      p0.y = (unsigned)f2bf(fv[0].z) | ((unsigned)f2bf(fv[0].w) << 16);
      p1.x = (unsigned)f2bf(fv[1].x) | ((unsigned)f2bf(fv[1].y) << 16);
      p1.y = (unsigned)f2bf(fv[1].z) | ((unsigned)f2bf(fv[1].w) << 16);
      *(uint2*)&Bs[nxt][bn_r0][bkc0 * 4] = p0;
      *(uint2*)&Bs[nxt][bn_r1][bkc1 * 4] = p1;
    }
  }
#pragma unroll
  for (int mf = 0; mf < 4; ++mf) {
#pragma unroll
    for (int i = 0; i < 4; ++i) {
      int m = w * 64 + mf * 16 + (l >> 4) * 4 + i;
      float v[4];
#pragma unroll
      for (int nf = 0; nf < 4; ++nf) {
        int n = bn + nf * 16 + (l & 15);
        float val = -3.4e38f;
        if (n < N) {
          val = acc[mf][nf][i] + bias[n];
          C[(size_t)m * N + n] = val;
        }
        v[nf] = val;
      }
      float mv = fmaxf(fmaxf(v[0], v[1]), fmaxf(v[2], v[3]));
#pragma unroll
      for (int off = 1; off < 16; off <<= 1) mv = fmaxf(mv, __shfl_xor(mv, off));
      float se = 0.f;
#pragma unroll
      for (int nf = 0; nf < 4; ++nf) se += (v[nf] > -1e38f) ? expf(v[nf] - mv) : 0.f;
#pragma unroll
      for (int off = 1; off < 16; off <<= 1) se += __shfl_xor(se, off);
      if ((l & 15) == 0) {
        pmax[(size_t)m * NT_OUT + bx] = mv;
        psum[(size_t)m * NT_OUT + bx] = se;
      }
    }
  }
}

// ---------------- combine partials -> stats ----------------
__global__ __launch_bounds__(256) void lsm_combine(const float* __restrict__ pmax,
                                                   const float* __restrict__ psum,
                                                   float* __restrict__ stats) {
  const int r = blockIdx.x, tid = threadIdx.x, w = tid >> 6, l = tid & 63;
  __shared__ float red[4];
  __shared__ float Msh;
  const float* pm = pmax + (size_t)r * NT_OUT;
  const float* ps = psum + (size_t)r * NT_OUT;
  float m = -3.4e38f;
  for (int j = tid; j < NT_OUT; j += 256) m = fmaxf(m, pm[j]);
#pragma unroll
  for (int off = 32; off; off >>= 1) m = fmaxf(m, __shfl_xor(m, off));
  if (l == 0) red[w] = m;
  __syncthreads();
  if (tid == 0) Msh = fmaxf(fmaxf(red[0], red[1]), fmaxf(red[2], red[3]));
  __syncthreads();
  float M = Msh;
  float s = 0.f;
  for (int j = tid; j < NT_OUT; j += 256) s += ps[j] * expf(pm[j] - M);
#pragma unroll
  for (int off = 32; off; off >>= 1) s += __shfl_xor(s, off);
  if (l == 0) red[w] = s;
  __syncthreads();
  if (tid == 0) {
    stats[r] = M;
    stats[256 + r] = logf(red[0] + red[1] + red[2] + red[3]);
  }
}

__global__ __launch_bounds__(256) void lsm_apply(float* __restrict__ C, const float* __restrict__ stats, int N) {
  int r = blockIdx.y;
  int ci = blockIdx.x * 256 + threadIdx.x;
  if (ci < N) {
    size_t idx = (size_t)r * N + ci;
    C[idx] = C[idx] - stats[r] - stats[256 + r];
  }
}

extern "C" void kernel_launch(void* const* d_in, const int* in_sizes, int n_in,
                              void* d_out, int out_size, void* d_ws, size_t ws_size,
                              hipStream_t stream) {
  (void)in_sizes; (void)n_in; (void)out_size; (void)ws_size;
  const int* motion = (const int*)d_in[0];
  const int* tgt = (const int*)d_in[1];
  const float* enc_emb = (const float*)d_in[2];
  const float* enc_Wih = (const float*)d_in[3];
  const float* enc_Whh = (const float*)d_in[4];
  const float* enc_bih = (const float*)d_in[5];
  const float* enc_bhh = (const float*)d_in[6];
  const float* dec_emb = (const float*)d_in[7];
  const float* dec_Wih = (const float*)d_in[8];
  const float* dec_Whh = (const float*)d_in[9];
  const float* dec_bih = (const float*)d_in[10];
  const float* dec_bhh = (const float*)d_in[11];
  const float* attn_W = (const float*)d_in[12];
  const float* attn_b = (const float*)d_in[13];
  const float* comb_W = (const float*)d_in[14];
  const float* comb_b = (const float*)d_in[15];
  const float* out_W = (const float*)d_in[16];
  const float* out_b = (const float*)d_in[17];
  float* out = (float*)d_out;

  // workspace layout (floats, 16B-aligned chunks)
  float* wsf = (float*)d_ws;
  size_t o = 0;
  auto F = [&](size_t n) { float* p = wsf + o; o += (n + 3) & ~(size_t)3; return p; };
  float* enc_gi = F(128 * 3072);
  float* enc_outs = F(128 * 1024);
  float* aE = F(256 * 128);
  float* xE = F(256 * 1024);
  float* P1 = F(256 * 3072);
  float* M2T = F(128 * 1024);
  float* Gm = F(3072 * 128);
  int* dec_tok = (int*)F(256);
  u64* epk = (u64*)F(HREP * 2048);            // [HREP][2][512] u64 packets } contiguous
  u64* dpk = (u64*)F(HREP * 2048);            //                            } for single
  unsigned* dflags = (unsigned*)F(FREP * 1024);  // [FREP][256] flags 64B   } memset
  float* a_acc = F(LC_ * AREP * 128);         // per-step 16-replica a accumulators
  float* stats = F(512);
  float* pmax = F(256 * NT_OUT);
  float* psum = F(256 * NT_OUT);
  unsigned short* Hs = (unsigned short*)F(256 * 1024 / 2);

  // fresh packets/flags/accumulators each launch (epk..a_acc contiguous)
  hipMemsetAsync(epk, 0, (HREP * 2048 + HREP * 2048 + FREP * 1024 + LC_ * AREP * 128) * sizeof(float), stream);

  // precompute (gather-fused GEMMs)
  build_dec_tok<<<1, 256, 0, stream>>>(tgt, dec_tok);
  gemm_g<<<dim3(48, 2), 256, 0, stream>>>(enc_emb, 512, motion, enc_Wih, 512, enc_bih, enc_gi, 3072, 512);
  gemm_dual<<<dim3(18, 4), 256, 0, stream>>>(dec_emb, 1024, dec_tok, comb_W, comb_b, attn_W, attn_b, xE, aE, 1024);
  gemm_g<<<dim3(48, 4), 256, 0, stream>>>(xE, 1024, nullptr, dec_Wih, 1024, dec_bih, P1, 3072, 1024);

  // encoder recurrence
  enc_rnn<<<NBLK, 256, 0, stream>>>(enc_Whh, enc_bhh, enc_gi, epk, enc_outs);

  // G = dec_Wih @ (comb_W[:,H:] @ enc_outs^T)
  gemm_g<<<dim3(16, 2), 256, 0, stream>>>(enc_outs, 1024, nullptr, comb_W + 1024, 2048, nullptr, M2T, 1024, 1024);
  gemm_g<<<dim3(2, 48), 256, 0, stream>>>(dec_Wih, 1024, nullptr, M2T, 1024, nullptr, Gm, 128, 1024);

  // decoder recurrence
  dec_rnn<<<NBLK, 256, 0, stream>>>(dec_Whh, dec_bhh, attn_W, Gm, P1, aE,
                                    enc_outs + (size_t)(LM_ - 1) * H_, a_acc, dpk, dflags, Hs);

  // output projection (+ fused softmax partials) + combine + apply
  out_gemm<<<NT_OUT, 256, 0, stream>>>(Hs, out_W, 1024, out_b, out, pmax, psum, V_, 1024);
  lsm_combine<<<256, 256, 0, stream>>>(pmax, psum, stats);
  lsm_apply<<<dim3(197, 256), 256, 0, stream>>>(out, stats, V_);
}

// Round 16
// 2201.941 us; speedup vs baseline: 1.1355x; 1.0574x over previous
//
#include <hip/hip_runtime.h>

// Problem dims
#define V_ 50257
#define E_ 512
#define H_ 1024
#define LM_ 128
#define LC_ 256
#define NBLK 256   // recurrence blocks: 1 per CU, 4 h-outputs each
#define ROWS 12    // 3 gates x 4 outputs
#define AREP 16    // a-accumulator replicas (contention divisor)
#define HREP 8     // encoder h-packet replicas (poll-contention divisor; dec reverted)
#define NT_OUT 786 // out_gemm col-tiles

typedef __attribute__((ext_vector_type(8))) short short8;
typedef __attribute__((ext_vector_type(4))) float f32x4;
typedef unsigned long long u64;

__device__ __forceinline__ unsigned short f2bf(float x) {
  union { float f; unsigned u; } v; v.f = x;
  unsigned r = v.u + 0x7fffu + ((v.u >> 16) & 1u);   // round-to-nearest-even
  return (unsigned short)(r >> 16);
}
__device__ __forceinline__ float bflo(unsigned u) { union { unsigned u; float f; } v; v.u = u << 16; return v.f; }
__device__ __forceinline__ float bfhi(unsigned u) { union { unsigned u; float f; } v; v.u = u & 0xffff0000u; return v.f; }

__device__ __forceinline__ int grow4(int s, int i0) {
  return (s < 4) ? (i0 + s) : (s < 8) ? (1024 + i0 + (s - 4)) : (2048 + i0 + (s - 8));
}

// relaxed agent-scope ops (served at coherence point; no fences -> no L2 flush/inv)
__device__ __forceinline__ void st_u32(unsigned* p, unsigned v) {
  __hip_atomic_store(p, v, __ATOMIC_RELAXED, __HIP_MEMORY_SCOPE_AGENT);
}
__device__ __forceinline__ void st_u64(u64* p, u64 v) {
  __hip_atomic_store(p, v, __ATOMIC_RELAXED, __HIP_MEMORY_SCOPE_AGENT);
}
__device__ __forceinline__ u64 ld_u64(const u64* p) {
  return __hip_atomic_load(p, __ATOMIC_RELAXED, __HIP_MEMORY_SCOPE_AGENT);
}
__device__ __forceinline__ unsigned ld_u32(const unsigned* p) {
  return __hip_atomic_load(p, __ATOMIC_RELAXED, __HIP_MEMORY_SCOPE_AGENT);
}
__device__ __forceinline__ void atom_add_f32(float* p, float v) {
  (void)__hip_atomic_fetch_add(p, v, __ATOMIC_RELAXED, __HIP_MEMORY_SCOPE_AGENT);
}

// ---------------- decoder token table ----------------
__global__ void build_dec_tok(const int* __restrict__ tgt, int* __restrict__ dtok) {
  int t = threadIdx.x;
  dtok[t] = (t == 0) ? 0 : (t == 1 ? tgt[LC_ - 1] : tgt[t - 2]);
}

// ---------------- gathered f32 GEMM: C[M,N] = A[rows][K] @ B[N,K]^T + bias ----------------
__global__ __launch_bounds__(256) void gemm_g(const float* __restrict__ A, int lda,
                                              const int* __restrict__ ridx,
                                              const float* __restrict__ B, int ldb,
                                              const float* __restrict__ bias,
                                              float* __restrict__ C, int ldc, int K) {
  __shared__ float As[16][68];
  __shared__ float Bs[16][68];
  const int bm = blockIdx.y * 64, bn = blockIdx.x * 64;
  const int tid = threadIdx.x;
  const int tx = tid & 15, ty = tid >> 4;
  const int lm = tid & 63, lk = (tid >> 6) * 4;
  const int arow = ridx ? ridx[bm + lm] : (bm + lm);
  const float* Arow = A + (size_t)arow * lda;
  float acc[4][4] = {};
  for (int k0 = 0; k0 < K; k0 += 16) {
    float4 av = *(const float4*)&Arow[k0 + lk];
    float4 bv = *(const float4*)&B[(size_t)(bn + lm) * ldb + k0 + lk];
    As[lk + 0][lm] = av.x; As[lk + 1][lm] = av.y; As[lk + 2][lm] = av.z; As[lk + 3][lm] = av.w;
    Bs[lk + 0][lm] = bv.x; Bs[lk + 1][lm] = bv.y; Bs[lk + 2][lm] = bv.z; Bs[lk + 3][lm] = bv.w;
    __syncthreads();
#pragma unroll
    for (int kk = 0; kk < 16; ++kk) {
      float4 a4 = *(const float4*)&As[kk][ty * 4];
      float4 b4 = *(const float4*)&Bs[kk][tx * 4];
      acc[0][0] += a4.x * b4.x; acc[0][1] += a4.x * b4.y; acc[0][2] += a4.x * b4.z; acc[0][3] += a4.x * b4.w;
      acc[1][0] += a4.y * b4.x; acc[1][1] += a4.y * b4.y; acc[1][2] += a4.y * b4.z; acc[1][3] += a4.y * b4.w;
      acc[2][0] += a4.z * b4.x; acc[2][1] += a4.z * b4.y; acc[2][2] += a4.z * b4.z; acc[2][3] += a4.z * b4.w;
      acc[3][0] += a4.w * b4.x; acc[3][1] += a4.w * b4.y; acc[3][2] += a4.w * b4.z; acc[3][3] += a4.w * b4.w;
    }
    __syncthreads();
  }
#pragma unroll
  for (int i = 0; i < 4; ++i) {
#pragma unroll
    for (int j = 0; j < 4; ++j) {
      int gm = bm + ty * 4 + i, gn = bn + tx * 4 + j;
      float bv = bias ? bias[gn] : 0.f;
      C[(size_t)gm * ldc + gn] = acc[i][j] + bv;
    }
  }
}

// ---------------- dual-output gathered GEMM: xE (bx<16) and aE (bx>=16) from dec_emb ----
__global__ __launch_bounds__(256) void gemm_dual(const float* __restrict__ A, int lda,
                                                 const int* __restrict__ ridx,
                                                 const float* __restrict__ combW,
                                                 const float* __restrict__ comb_b,
                                                 const float* __restrict__ attnW,
                                                 const float* __restrict__ attn_b,
                                                 float* __restrict__ xE,
                                                 float* __restrict__ aE, int K) {
  __shared__ float As[16][68];
  __shared__ float Bs[16][68];
  const int bm = blockIdx.y * 64;
  const bool is_x = blockIdx.x < 16;
  const int bn = (is_x ? blockIdx.x : (blockIdx.x - 16)) * 64;
  const float* B = is_x ? combW : attnW;
  const int ldb = 2048;
  const float* bias = is_x ? comb_b : attn_b;
  float* C = is_x ? xE : aE;
  const int ldc = is_x ? 1024 : 128;
  const int tid = threadIdx.x;
  const int tx = tid & 15, ty = tid >> 4;
  const int lm = tid & 63, lk = (tid >> 6) * 4;
  const int arow = ridx[bm + lm];
  const float* Arow = A + (size_t)arow * lda;
  float acc[4][4] = {};
  for (int k0 = 0; k0 < K; k0 += 16) {
    float4 av = *(const float4*)&Arow[k0 + lk];
    float4 bv = *(const float4*)&B[(size_t)(bn + lm) * ldb + k0 + lk];
    As[lk + 0][lm] = av.x; As[lk + 1][lm] = av.y; As[lk + 2][lm] = av.z; As[lk + 3][lm] = av.w;
    Bs[lk + 0][lm] = bv.x; Bs[lk + 1][lm] = bv.y; Bs[lk + 2][lm] = bv.z; Bs[lk + 3][lm] = bv.w;
    __syncthreads();
#pragma unroll
    for (int kk = 0; kk < 16; ++kk) {
      float4 a4 = *(const float4*)&As[kk][ty * 4];
      float4 b4 = *(const float4*)&Bs[kk][tx * 4];
      acc[0][0] += a4.x * b4.x; acc[0][1] += a4.x * b4.y; acc[0][2] += a4.x * b4.z; acc[0][3] += a4.x * b4.w;
      acc[1][0] += a4.y * b4.x; acc[1][1] += a4.y * b4.y; acc[1][2] += a4.y * b4.z; acc[1][3] += a4.y * b4.w;
      acc[2][0] += a4.z * b4.x; acc[2][1] += a4.z * b4.y; acc[2][2] += a4.z * b4.z; acc[2][3] += a4.z * b4.w;
      acc[3][0] += a4.w * b4.x; acc[3][1] += a4.w * b4.y; acc[3][2] += a4.w * b4.z; acc[3][3] += a4.w * b4.w;
    }
    __syncthreads();
  }
#pragma unroll
  for (int i = 0; i < 4; ++i) {
#pragma unroll
    for (int j = 0; j < 4; ++j) {
      int gm = bm + ty * 4 + i, gn = bn + tx * 4 + j;
      C[(size_t)gm * ldc + gn] = acc[i][j] + bias[gn];
    }
  }
}

// ---------------- encoder recurrence: 8x-replicated self-validating packets ----------------
__global__ __launch_bounds__(256) void enc_rnn(const float* __restrict__ Whh,
                                               const float* __restrict__ bhh,
                                               const float* __restrict__ gi,
                                               u64* __restrict__ epk,
                                               float* __restrict__ outs) {
  __shared__ unsigned short Whl[ROWS][1024];  // 24 KB
  __shared__ unsigned h_sh[512];
  __shared__ float h_own[4];
  __shared__ float bh[ROWS];
  __shared__ float ghl[ROWS];
  const int b = blockIdx.x, tid = threadIdx.x;
  const int w = tid >> 6, l = tid & 63;
  const int i0 = b * 4;
  const u64* myrep = epk + (size_t)(b & (HREP - 1)) * 1024;
  for (int idx = tid; idx < ROWS * 1024; idx += 256) {
    int s = idx >> 10, c = idx & 1023;
    Whl[s][c] = f2bf(Whh[(size_t)grow4(s, i0) * H_ + c]);
  }
  if (tid < ROWS) bh[tid] = bhh[grow4(tid, i0)];
  if (tid < 4) h_own[tid] = 0.f;
  __syncthreads();

  for (int t = 0; t < LM_; ++t) {
    float gr = 0.f, gz = 0.f, gn_ = 0.f;
    if (tid < 4) {
      const float* git = gi + (size_t)t * 3072;
      gr = git[i0 + tid]; gz = git[1024 + i0 + tid]; gn_ = git[2048 + i0 + tid];
    }
    if (t == 0) {
      h_sh[2 * tid] = 0u; h_sh[2 * tid + 1] = 0u;
    } else {
      const u64* pb = myrep + (size_t)(t & 1) * 512 + 2 * tid;
      const unsigned g = (unsigned)t;
      u64 q0, q1;
      for (;;) {
        q0 = ld_u64(pb); q1 = ld_u64(pb + 1);
        if ((unsigned)(q0 >> 32) == g && (unsigned)(q1 >> 32) == g) break;
        __builtin_amdgcn_s_sleep(1);
      }
      h_sh[2 * tid] = (unsigned)q0;
      h_sh[2 * tid + 1] = (unsigned)q1;
    }
    __syncthreads();

    for (int s = w; s < ROWS; s += 4) {
      float acc = 0.f;
#pragma unroll
      for (int e = 0; e < 8; ++e) {
        unsigned u = *(const unsigned*)&Whl[s][2 * (e * 64 + l)];
        unsigned hv = h_sh[e * 64 + l];
        acc += bflo(u) * bflo(hv) + bfhi(u) * bfhi(hv);
      }
#pragma unroll
      for (int off = 32; off; off >>= 1) acc += __shfl_xor(acc, off);
      if (l == 0) ghl[s] = acc;
    }
    __syncthreads();
    if (tid < 4) {
      int i = tid, ig = i0 + i;
      float hr = ghl[i] + bh[i], hz = ghl[4 + i] + bh[4 + i], hn = ghl[8 + i] + bh[8 + i];
      float r = 1.f / (1.f + expf(-(gr + hr)));
      float z = 1.f / (1.f + expf(-(gz + hz)));
      float n = tanhf(gn_ + r * hn);
      float hpv = (1.f - z) * n + z * h_own[i];
      h_own[i] = hpv;
      float v0 = __shfl(hpv, 0), v1 = __shfl(hpv, 1);
      float v2 = __shfl(hpv, 2), v3 = __shfl(hpv, 3);
      if (tid == 0) {
        u64 gg = (u64)(unsigned)(t + 1) << 32;
        u64 p0 = gg | (u64)((unsigned)f2bf(v0) | ((unsigned)f2bf(v1) << 16));
        u64 p1 = gg | (u64)((unsigned)f2bf(v2) | ((unsigned)f2bf(v3) << 16));
        size_t slot = (size_t)((t + 1) & 1) * 512 + 2 * b;
#pragma unroll
        for (int r2 = 0; r2 < HREP; ++r2) {
          st_u64(epk + (size_t)r2 * 1024 + slot, p0);
          st_u64(epk + (size_t)r2 * 1024 + slot + 1, p1);
        }
      }
      outs[(size_t)t * H_ + ig] = hpv;
    }
  }
}

// ---------------- decoder recurrence (R14 config): single packets/flags, spec a-read ----
__global__ __launch_bounds__(256) void dec_rnn(const float* __restrict__ Whh,
                                               const float* __restrict__ bhh,
                                               const float* __restrict__ attn_W,
                                               const float* __restrict__ G,
                                               const float* __restrict__ P1,
                                               const float* __restrict__ aE,
                                               const float* __restrict__ hfin,
                                               float* __restrict__ a_acc,
                                               u64* __restrict__ dpk,
                                               unsigned* __restrict__ dflags,
                                               unsigned short* __restrict__ Hs) {
  __shared__ unsigned short Whl[ROWS][1024];  // 24 KB
  __shared__ unsigned Ac[2 * 128];            // 1 KB
  __shared__ float Gl[ROWS][128];             // 6 KB
  __shared__ unsigned h_sh[512];              // 2 KB
  __shared__ float a_f[128];
  __shared__ float h_own[4];
  __shared__ float bh[ROWS];
  __shared__ float ghl[ROWS];
  __shared__ float giS[ROWS];
  const int b = blockIdx.x, tid = threadIdx.x;
  const int w = tid >> 6, l = tid & 63;
  const int i0 = b * 4;
  for (int idx = tid; idx < ROWS * 1024; idx += 256) {
    int s = idx >> 10, c = idx & 1023;
    Whl[s][c] = f2bf(Whh[(size_t)grow4(s, i0) * H_ + c]);
  }
  if (tid < 256) {
    int u = tid >> 7, j = tid & 127;
    float2 wv = *(const float2*)&attn_W[(size_t)j * 2048 + 1024 + i0 + 2 * u];
    Ac[tid] = (unsigned)f2bf(wv.x) | ((unsigned)f2bf(wv.y) << 16);
  }
  for (int idx = tid; idx < ROWS * 128; idx += 256) {
    int s = idx >> 7, c = idx & 127;
    Gl[s][c] = G[(size_t)grow4(s, i0) * 128 + c];
  }
  if (tid < ROWS) bh[tid] = bhh[grow4(tid, i0)];
  if (tid < 4) h_own[tid] = hfin[i0 + tid];   // exact f32 encoder-final h
  __syncthreads();

  // prologue: a-partial adds for t=0 from own h0 chunk, then a-flag = 1
  {
    float h0 = h_own[0], h1 = h_own[1], h2 = h_own[2], h3 = h_own[3];
    if (tid < 128) {
      unsigned w0 = Ac[tid], w1 = Ac[128 + tid];
      float a0 = bflo(w0) * h0 + bfhi(w0) * h1 + bflo(w1) * h2 + bfhi(w1) * h3;
      atom_add_f32(&a_acc[(b & (AREP - 1)) * 128 + tid], a0);
    }
    __syncthreads();  // drain atomics
    if (tid == 0) st_u32(&dflags[b * 16], 1u);
  }

  for (int t = 0; t < LC_; ++t) {
    // ---- wave0: flag check (one-shot in steady state) + issue a_acc/aE loads ----
    u64 aacc[16]; u64 aEv = 0;
    if (tid < 64) {
      const unsigned need = (unsigned)(t + 1);
      for (;;) {
        unsigned f0 = ld_u32(&dflags[tid * 16]);
        unsigned f1 = ld_u32(&dflags[(tid + 64) * 16]);
        unsigned f2 = ld_u32(&dflags[(tid + 128) * 16]);
        unsigned f3 = ld_u32(&dflags[(tid + 192) * 16]);
        unsigned mn = min(min(f0, f1), min(f2, f3));
        if (__all((int)(mn >= need))) break;
        __builtin_amdgcn_s_sleep(1);
      }
      const u64* ab = (const u64*)(a_acc + (size_t)t * (AREP * 128)) + l;
#pragma unroll
      for (int r = 0; r < AREP; ++r) aacc[r] = ld_u64(ab + r * 64);
      float2 ae2 = *(const float2*)&aE[(size_t)t * LM_ + 2 * l];
      aEv = ((u64)__float_as_uint(ae2.y) << 32) | (u64)__float_as_uint(ae2.x);
    }
    // ---- prefetch P1 (independent of h) ----
    float p1p[3];
    if (l == 0) {
#pragma unroll
      for (int k = 0; k < 3; ++k) p1p[k] = P1[(size_t)t * 3072 + grow4(w + 4 * k, i0)];
    } else {
      p1p[0] = p1p[1] = p1p[2] = 0.f;
    }
    // ---- h arrival: self-validating packet poll (t=0: hfin) ----
    if (t == 0) {
      float4 hv = ((const float4*)hfin)[tid];
      h_sh[2 * tid] = (unsigned)f2bf(hv.x) | ((unsigned)f2bf(hv.y) << 16);
      h_sh[2 * tid + 1] = (unsigned)f2bf(hv.z) | ((unsigned)f2bf(hv.w) << 16);
    } else {
      const u64* pb = dpk + (size_t)(t & 1) * 512 + 2 * tid;
      const unsigned g = (unsigned)t;
      u64 q0, q1;
      for (;;) {
        q0 = ld_u64(pb); q1 = ld_u64(pb + 1);
        if ((unsigned)(q0 >> 32) == g && (unsigned)(q1 >> 32) == g) break;
        __builtin_amdgcn_s_sleep(1);
      }
      h_sh[2 * tid] = (unsigned)q0;
      h_sh[2 * tid + 1] = (unsigned)q1;
    }
    __syncthreads();  // B1

    // ---- wave0: finish a_f from in-flight loads; all: gh rows ----
    if (tid < 64) {
      float s0 = 0.f, s1 = 0.f;
#pragma unroll
      for (int r = 0; r < AREP; ++r) {
        s0 += __uint_as_float((unsigned)aacc[r]);
        s1 += __uint_as_float((unsigned)(aacc[r] >> 32));
      }
      a_f[2 * l] = s0 + __uint_as_float((unsigned)aEv);
      a_f[2 * l + 1] = s1 + __uint_as_float((unsigned)(aEv >> 32));
    }
    for (int s = w; s < ROWS; s += 4) {
      float acc = 0.f;
#pragma unroll
      for (int e = 0; e < 8; ++e) {
        unsigned u = *(const unsigned*)&Whl[s][2 * (e * 64 + l)];
        unsigned hv = h_sh[e * 64 + l];
        acc += bflo(u) * bflo(hv) + bfhi(u) * bfhi(hv);
      }
#pragma unroll
      for (int off = 32; off; off >>= 1) acc += __shfl_xor(acc, off);
      if (l == 0) ghl[s] = acc;
    }
    __syncthreads();  // B2

    // ---- softmax over a[128] (per-wave redundant) + gi = P1 + G.w ----
    float ax = a_f[2 * l], ay = a_f[2 * l + 1];
    float mx = fmaxf(ax, ay);
#pragma unroll
    for (int off = 32; off; off >>= 1) mx = fmaxf(mx, __shfl_xor(mx, off));
    float pe0 = expf(ax - mx), pe1 = expf(ay - mx);
    float zs = pe0 + pe1;
#pragma unroll
    for (int off = 32; off; off >>= 1) zs += __shfl_xor(zs, off);
    float w0 = pe0 / zs, w1 = pe1 / zs;
#pragma unroll
    for (int k = 0; k < 3; ++k) {
      int s = w + 4 * k;
      float2 g2 = *(const float2*)&Gl[s][2 * l];
      float acc = g2.x * w0 + g2.y * w1;
#pragma unroll
      for (int off = 32; off; off >>= 1) acc += __shfl_xor(acc, off);
      if (l == 0) giS[s] = acc + p1p[k];
    }
    __syncthreads();  // B3

    // ---- gates + h-packet publish ----
    if (tid < 4) {
      int i = tid, ig = i0 + i;
      float hr = ghl[i] + bh[i], hz = ghl[4 + i] + bh[4 + i], hn = ghl[8 + i] + bh[8 + i];
      float r = 1.f / (1.f + expf(-(giS[i] + hr)));
      float z = 1.f / (1.f + expf(-(giS[4 + i] + hz)));
      float n = tanhf(giS[8 + i] + r * hn);
      float hpv = (1.f - z) * n + z * h_own[i];
      h_own[i] = hpv;
      float v0 = __shfl(hpv, 0), v1 = __shfl(hpv, 1);
      float v2 = __shfl(hpv, 2), v3 = __shfl(hpv, 3);
      if (tid == 0 && t < LC_ - 1) {
        u64 gg = (u64)(unsigned)(t + 1) << 32;
        u64* pb = dpk + (size_t)((t + 1) & 1) * 512 + 2 * b;
        st_u64(pb,     gg | (u64)((unsigned)f2bf(v0) | ((unsigned)f2bf(v1) << 16)));
        st_u64(pb + 1, gg | (u64)((unsigned)f2bf(v2) | ((unsigned)f2bf(v3) << 16)));
      }
      Hs[(size_t)t * H_ + ig] = f2bf(hpv);
    }
    __syncthreads();  // B4: h_own visible

    // ---- a-partial atomics for t+1 (replica b&15), then flag ----
    if (t < LC_ - 1) {
      float h0 = h_own[0], h1 = h_own[1], h2 = h_own[2], h3 = h_own[3];
      if (tid < 128) {
        unsigned w0p = Ac[tid], w1p = Ac[128 + tid];
        float a0 = bflo(w0p) * h0 + bfhi(w0p) * h1 + bflo(w1p) * h2 + bfhi(w1p) * h3;
        atom_add_f32(&a_acc[(size_t)(t + 1) * (AREP * 128) + (b & (AREP - 1)) * 128 + tid], a0);
      }
    }
    __syncthreads();  // B5: drain atomics
    if (tid == 0) st_u32(&dflags[b * 16], (unsigned)(t + 2));
  }
}

// ---------------- MFMA GEMM (double-buffered) + fused softmax partials ----------------
__global__ __launch_bounds__(256) void out_gemm(const unsigned short* __restrict__ A,
                                                const float* __restrict__ Wf, int ldw,
                                                const float* __restrict__ bias,
                                                float* __restrict__ C,
                                                float* __restrict__ pmax,
                                                float* __restrict__ psum,
                                                int N, int K) {
  __shared__ unsigned short As[2][256][40];
  __shared__ unsigned short Bs[2][64][40];
  const int bn = blockIdx.x * 64, bx = blockIdx.x;
  const int tid = threadIdx.x, w = tid >> 6, l = tid & 63;
  const int NIT = K / 32;
  f32x4 acc[4][4];
#pragma unroll
  for (int mf = 0; mf < 4; ++mf)
#pragma unroll
    for (int nf = 0; nf < 4; ++nf) acc[mf][nf] = (f32x4){0.f, 0.f, 0.f, 0.f};

  const int bn_r0 = (tid) >> 3, bkc0 = tid & 7;
  const int bn_r1 = (tid + 256) >> 3, bkc1 = (tid + 256) & 7;

  short8 ar[4];
  float4 fv[2];
  // prologue: load iter 0
  {
    const unsigned short* src = A + (size_t)tid * K;
#pragma unroll
    for (int kc = 0; kc < 4; ++kc) ar[kc] = *(const short8*)(src + kc * 8);
    int gn0 = bn + bn_r0, gn1 = bn + bn_r1;
    fv[0] = (gn0 < N) ? *(const float4*)&Wf[(size_t)gn0 * ldw + bkc0 * 4] : (float4){0, 0, 0, 0};
    fv[1] = (gn1 < N) ? *(const float4*)&Wf[(size_t)gn1 * ldw + bkc1 * 4] : (float4){0, 0, 0, 0};
#pragma unroll
    for (int kc = 0; kc < 4; ++kc) *(short8*)&As[0][tid][kc * 8] = ar[kc];
    uint2 p0, p1;
    p0.x = (unsigned)f2bf(fv[0].x) | ((unsigned)f2bf(fv[0].y) << 16);
    p0.y = (unsigned)f2bf(fv[0].z) | ((unsigned)f2bf(fv[0].w) << 16);
    p1.x = (unsigned)f2bf(fv[1].x) | ((unsigned)f2bf(fv[1].y) << 16);
    p1.y = (unsigned)f2bf(fv[1].z) | ((unsigned)f2bf(fv[1].w) << 16);
    *(uint2*)&Bs[0][bn_r0][bkc0 * 4] = p0;
    *(uint2*)&Bs[0][bn_r1][bkc1 * 4] = p1;
  }

  for (int it = 0; it < NIT; ++it) {
    const int cur = it & 1, nxt = cur ^ 1;
    __syncthreads();
    if (it + 1 < NIT) {
      int k0n = (it + 1) * 32;
      const unsigned short* src = A + (size_t)tid * K + k0n;
#pragma unroll
      for (int kc = 0; kc < 4; ++kc) ar[kc] = *(const short8*)(src + kc * 8);
      int gn0 = bn + bn_r0, gn1 = bn + bn_r1;
      fv[0] = (gn0 < N) ? *(const float4*)&Wf[(size_t)gn0 * ldw + k0n + bkc0 * 4] : (float4){0, 0, 0, 0};
      fv[1] = (gn1 < N) ? *(const float4*)&Wf[(size_t)gn1 * ldw + k0n + bkc1 * 4] : (float4){0, 0, 0, 0};
    }
    const int k8 = (l >> 4) * 8;
    short8 af4[4], bf4[4];
#pragma unroll
    for (int mf = 0; mf < 4; ++mf) af4[mf] = *(const short8*)&As[cur][w * 64 + mf * 16 + (l & 15)][k8];
#pragma unroll
    for (int nf = 0; nf < 4; ++nf) bf4[nf] = *(const short8*)&Bs[cur][nf * 16 + (l & 15)][k8];
#pragma unroll
    for (int mf = 0; mf < 4; ++mf)
#pragma unroll
      for (int nf = 0; nf < 4; ++nf)
        acc[mf][nf] = __builtin_amdgcn_mfma_f32_16x16x32_bf16(af4[mf], bf4[nf], acc[mf][nf], 0, 0, 0);
    if (it + 1 < NIT) {
#pragma unroll
      for (int kc = 0; kc < 4; ++kc) *(short8*)&As[nxt][tid][kc * 8] = ar[kc];
      uint2 p0, p1;
      p0.x = (unsigned)f2bf(fv[0].x) | ((unsigned)f2bf(fv[0].y) << 16);
      p0.y = (unsigned)f2bf(fv[0].z) | ((unsigned)f2bf(fv[0].w) << 16);
      p1.x = (unsigned)f2bf(fv[1].x) | ((unsigned)f2bf(fv[1].y) << 16);
      p1.y = (unsigned)f2bf(fv[1].z) | ((unsigned)f2bf(fv[1].w) << 16);
      *(uint2*)&Bs[nxt][bn_r0][bkc0 * 4] = p0;
      *(uint2*)&Bs[nxt][bn_r1][bkc1 * 4] = p1;
    }
  }
#pragma unroll
  for (int mf = 0; mf < 4; ++mf) {
#pragma unroll
    for (int i = 0; i < 4; ++i) {
      int m = w * 64 + mf * 16 + (l >> 4) * 4 + i;
      float v[4];
#pragma unroll
      for (int nf = 0; nf < 4; ++nf) {
        int n = bn + nf * 16 + (l & 15);
        float val = -3.4e38f;
        if (n < N) {
          val = acc[mf][nf][i] + bias[n];
          C[(size_t)m * N + n] = val;
        }
        v[nf] = val;
      }
      float mv = fmaxf(fmaxf(v[0], v[1]), fmaxf(v[2], v[3]));
#pragma unroll
      for (int off = 1; off < 16; off <<= 1) mv = fmaxf(mv, __shfl_xor(mv, off));
      float se = 0.f;
#pragma unroll
      for (int nf = 0; nf < 4; ++nf) se += (v[nf] > -1e38f) ? expf(v[nf] - mv) : 0.f;
#pragma unroll
      for (int off = 1; off < 16; off <<= 1) se += __shfl_xor(se, off);
      if ((l & 15) == 0) {
        pmax[(size_t)m * NT_OUT + bx] = mv;
        psum[(size_t)m * NT_OUT + bx] = se;
      }
    }
  }
}

// ---------------- combine partials -> stats ----------------
__global__ __launch_bounds__(256) void lsm_combine(const float* __restrict__ pmax,
                                                   const float* __restrict__ psum,
                                                   float* __restrict__ stats) {
  const int r = blockIdx.x, tid = threadIdx.x, w = tid >> 6, l = tid & 63;
  __shared__ float red[4];
  __shared__ float Msh;
  const float* pm = pmax + (size_t)r * NT_OUT;
  const float* ps = psum + (size_t)r * NT_OUT;
  float m = -3.4e38f;
  for (int j = tid; j < NT_OUT; j += 256) m = fmaxf(m, pm[j]);
#pragma unroll
  for (int off = 32; off; off >>= 1) m = fmaxf(m, __shfl_xor(m, off));
  if (l == 0) red[w] = m;
  __syncthreads();
  if (tid == 0) Msh = fmaxf(fmaxf(red[0], red[1]), fmaxf(red[2], red[3]));
  __syncthreads();
  float M = Msh;
  float s = 0.f;
  for (int j = tid; j < NT_OUT; j += 256) s += ps[j] * expf(pm[j] - M);
#pragma unroll
  for (int off = 32; off; off >>= 1) s += __shfl_xor(s, off);
  if (l == 0) red[w] = s;
  __syncthreads();
  if (tid == 0) {
    stats[r] = M;
    stats[256 + r] = logf(red[0] + red[1] + red[2] + red[3]);
  }
}

__global__ __launch_bounds__(256) void lsm_apply(float* __restrict__ C, const float* __restrict__ stats, int N) {
  int r = blockIdx.y;
  int ci = blockIdx.x * 256 + threadIdx.x;
  if (ci < N) {
    size_t idx = (size_t)r * N + ci;
    C[idx] = C[idx] - stats[r] - stats[256 + r];
  }
}

extern "C" void kernel_launch(void* const* d_in, const int* in_sizes, int n_in,
                              void* d_out, int out_size, void* d_ws, size_t ws_size,
                              hipStream_t stream) {
  (void)in_sizes; (void)n_in; (void)out_size; (void)ws_size;
  const int* motion = (const int*)d_in[0];
  const int* tgt = (const int*)d_in[1];
  const float* enc_emb = (const float*)d_in[2];
  const float* enc_Wih = (const float*)d_in[3];
  const float* enc_Whh = (const float*)d_in[4];
  const float* enc_bih = (const float*)d_in[5];
  const float* enc_bhh = (const float*)d_in[6];
  const float* dec_emb = (const float*)d_in[7];
  const float* dec_Wih = (const float*)d_in[8];
  const float* dec_Whh = (const float*)d_in[9];
  const float* dec_bih = (const float*)d_in[10];
  const float* dec_bhh = (const float*)d_in[11];
  const float* attn_W = (const float*)d_in[12];
  const float* attn_b = (const float*)d_in[13];
  const float* comb_W = (const float*)d_in[14];
  const float* comb_b = (const float*)d_in[15];
  const float* out_W = (const float*)d_in[16];
  const float* out_b = (const float*)d_in[17];
  float* out = (float*)d_out;

  // workspace layout (floats, 16B-aligned chunks)
  float* wsf = (float*)d_ws;
  size_t o = 0;
  auto F = [&](size_t n) { float* p = wsf + o; o += (n + 3) & ~(size_t)3; return p; };
  float* enc_gi = F(128 * 3072);
  float* enc_outs = F(128 * 1024);
  float* aE = F(256 * 128);
  float* xE = F(256 * 1024);
  float* P1 = F(256 * 3072);
  float* M2T = F(128 * 1024);
  float* Gm = F(3072 * 128);
  int* dec_tok = (int*)F(256);
  u64* epk = (u64*)F(HREP * 2048);            // [HREP][2][512] u64 packets } contiguous
  u64* dpk = (u64*)F(2048);                   // [2][512] u64 packets       } for single
  unsigned* dflags = (unsigned*)F(4096);      // 256 flags, 64B apart       } memset
  float* a_acc = F(LC_ * AREP * 128);         // per-step 16-replica a accumulators
  float* stats = F(512);
  float* pmax = F(256 * NT_OUT);
  float* psum = F(256 * NT_OUT);
  unsigned short* Hs = (unsigned short*)F(256 * 1024 / 2);

  // fresh packets/flags/accumulators each launch (epk..a_acc contiguous)
  hipMemsetAsync(epk, 0, (HREP * 2048 + 2048 + 4096 + LC_ * AREP * 128) * sizeof(float), stream);

  // precompute (gather-fused GEMMs)
  build_dec_tok<<<1, 256, 0, stream>>>(tgt, dec_tok);
  gemm_g<<<dim3(48, 2), 256, 0, stream>>>(enc_emb, 512, motion, enc_Wih, 512, enc_bih, enc_gi, 3072, 512);
  gemm_dual<<<dim3(18, 4), 256, 0, stream>>>(dec_emb, 1024, dec_tok, comb_W, comb_b, attn_W, attn_b, xE, aE, 1024);
  gemm_g<<<dim3(48, 4), 256, 0, stream>>>(xE, 1024, nullptr, dec_Wih, 1024, dec_bih, P1, 3072, 1024);

  // encoder recurrence (replicated packets)
  enc_rnn<<<NBLK, 256, 0, stream>>>(enc_Whh, enc_bhh, enc_gi, epk, enc_outs);

  // G = dec_Wih @ (comb_W[:,H:] @ enc_outs^T)
  gemm_g<<<dim3(16, 2), 256, 0, stream>>>(enc_outs, 1024, nullptr, comb_W + 1024, 2048, nullptr, M2T, 1024, 1024);
  gemm_g<<<dim3(2, 48), 256, 0, stream>>>(dec_Wih, 1024, nullptr, M2T, 1024, nullptr, Gm, 128, 1024);

  // decoder recurrence (R14 single-copy config)
  dec_rnn<<<NBLK, 256, 0, stream>>>(dec_Whh, dec_bhh, attn_W, Gm, P1, aE,
                                    enc_outs + (size_t)(LM_ - 1) * H_, a_acc, dpk, dflags, Hs);

  // output projection (+ fused softmax partials) + combine + apply
  out_gemm<<<NT_OUT, 256, 0, stream>>>(Hs, out_W, 1024, out_b, out, pmax, psum, V_, 1024);
  lsm_combine<<<256, 256, 0, stream>>>(pmax, psum, stats);
  lsm_apply<<<dim3(197, 256), 256, 0, stream>>>(out, stats, V_);
}